// Round 2
// baseline (1008.377 us; speedup 1.0000x reference)
//
#include <hip/hip_runtime.h>
#include <stdint.h>

using u16 = unsigned short;
using u32 = unsigned int;

#define S_DIM 512
#define N_DIM 256
#define CM 64
#define CZ 128
#define COPM 32
#define CHN 32
#define NH 8
#define NPOS (S_DIM*N_DIM)       // 131072 positions (s,n)
#define NPAIR (N_DIM*N_DIM)      // 65536 pairs (i,j)
#define CHS 128                  // s-chunk
#define CHPOS (CHS*N_DIM)        // 32768
#define ICH 64                   // i-chunk for zt
#define ICH_ROWS (ICH*COPM)      // 2048 rows of big zt matrix per chunk
#define ICH_PAIR (ICH*N_DIM)     // 16384 pairs per chunk

__device__ __forceinline__ float b2f(u16 h){ u32 u = ((u32)h)<<16; float f; __builtin_memcpy(&f,&u,4); return f; }
__device__ __forceinline__ u16 f2b(float f){ u32 u; __builtin_memcpy(&u,&f,4); u32 r = (u + 0x7fffu + ((u>>16)&1u))>>16; return (u16)r; }

typedef __bf16 bf16_t;
typedef bf16_t bf16x8 __attribute__((ext_vector_type(8)));
typedef float  f32x4  __attribute__((ext_vector_type(4)));

struct EpiArgs {
  const float* rowscale;   // msa_mask per output row
  const float* addz;       // z (fp32)
  const float* obias;      // opm_o_b (fp32)
  const float* recip;      // 1/num_mask
  u16*  out_b;
  float* out_f;
  int ldc;
  int ic;
};

constexpr int EPI_PLAIN=0, EPI_ROWSCALE=1, EPI_SIGMOID=2, EPI_VT=3, EPI_ZTP=4, EPI_ZNEW=5, EPI_O=6;

// Generic C[M,N] = A[M,K] * W[N,K]^T, bf16 in, fp32 accum. BK=64.
// 4 waves arranged WR x WC, each wave computes a 64x64 subtile (4x4 frags of 16x16x32).
template<int BM,int BN,int WR,int WC,int EPI>
__global__ __launch_bounds__(256) void gemm_k(const u16* __restrict__ A, const u16* __restrict__ W,
                                              int K, size_t sAz, size_t sWz, EpiArgs ea)
{
  __shared__ __align__(16) u16 lsA[BM*64];
  __shared__ __align__(16) u16 lsW[BN*64];
  const int tid  = threadIdx.x;
  const int lane = tid & 63;
  const int wv   = tid >> 6;
  const int wr   = wv / WC;
  const int wc   = wv % WC;
  const int m0   = blockIdx.y * BM;
  const int n0   = blockIdx.x * BN;
  const u16* Ab = A + (size_t)blockIdx.z * sAz + (size_t)m0 * K;
  const u16* Wb = W + (size_t)blockIdx.z * sWz + (size_t)n0 * K;

  f32x4 acc[4][4];
  const f32x4 zf = {0.f,0.f,0.f,0.f};
  #pragma unroll
  for (int i=0;i<4;i++)
    #pragma unroll
    for (int j=0;j<4;j++) acc[i][j] = zf;

  const int nkt = K >> 6;
  for (int kt = 0; kt < nkt; ++kt) {
    // ---- stage A,W tiles (16B chunks), XOR-swizzled rows (G4 fix for 128B-stride reads)
    for (int c = tid; c < (BM+BN)*8; c += 256) {
      if (c < BM*8) {
        int row = c>>3, kc = c&7;
        uint4 v = *reinterpret_cast<const uint4*>(Ab + (size_t)row*K + (kt<<6) + (kc<<3));
        *reinterpret_cast<uint4*>((char*)lsA + row*128 + ((kc<<4) ^ ((row&7)<<4))) = v;
      } else {
        int c2 = c - BM*8; int row = c2>>3, kc = c2&7;
        uint4 v = *reinterpret_cast<const uint4*>(Wb + (size_t)row*K + (kt<<6) + (kc<<3));
        *reinterpret_cast<uint4*>((char*)lsW + row*128 + ((kc<<4) ^ ((row&7)<<4))) = v;
      }
    }
    __syncthreads();
    #pragma unroll
    for (int kk=0; kk<2; ++kk) {
      const int kb = (kk<<6) + ((lane>>4)<<4);   // byte offset of this lane's 16B k-group
      bf16x8 af[4], wf[4];
      #pragma unroll
      for (int mf=0;mf<4;mf++){
        int row = wr*64 + mf*16 + (lane&15);
        af[mf] = *reinterpret_cast<const bf16x8*>((char*)lsA + row*128 + (kb ^ ((row&7)<<4)));
      }
      #pragma unroll
      for (int nf=0;nf<4;nf++){
        int row = wc*64 + nf*16 + (lane&15);
        wf[nf] = *reinterpret_cast<const bf16x8*>((char*)lsW + row*128 + (kb ^ ((row&7)<<4)));
      }
      #pragma unroll
      for (int mf=0;mf<4;mf++)
        #pragma unroll
        for (int nf=0;nf<4;nf++)
          acc[mf][nf] = __builtin_amdgcn_mfma_f32_16x16x32_bf16(af[mf], wf[nf], acc[mf][nf], 0,0,0);
    }
    __syncthreads();
  }

  // ---- epilogue. C/D frag: col = lane&15, row = (lane>>4)*4 + r   [m89-verified]
  const int hz = blockIdx.z;
  #pragma unroll
  for (int mf=0;mf<4;mf++){
    #pragma unroll
    for (int nf=0;nf<4;nf++){
      f32x4 v = acc[mf][nf];
      int col   = n0 + wc*64 + nf*16 + (lane&15);
      int rbase = m0 + wr*64 + mf*16 + ((lane>>4)<<2);
      #pragma unroll
      for (int r=0;r<4;r++){
        int row = rbase + r;
        float x = v[r];
        if constexpr (EPI==EPI_PLAIN) {
          ea.out_f[(size_t)row*ea.ldc + col] = x;
        } else if constexpr (EPI==EPI_ROWSCALE) {
          x *= ea.rowscale[row];
          ea.out_b[(size_t)row*ea.ldc + col] = f2b(x);
        } else if constexpr (EPI==EPI_SIGMOID) {
          x = 1.f/(1.f+__expf(-x));
          ea.out_b[(size_t)row*ea.ldc + col] = f2b(x);
        } else if constexpr (EPI==EPI_VT) {
          // row = s_l*256 + j ; col = h*32+c  ->  v_t[h][(s_l*32+c)][j]
          int hh = col>>5, cc = col&31, sl = row>>8, j = row&255;
          ea.out_b[((size_t)(hh*(CHS*CHN) + sl*CHN + cc))*N_DIM + j] = f2b(x);
        } else if constexpr (EPI==EPI_ZTP) {
          // row = i_l*32+c (chunk-local), col = j*32+d -> ztp[(i_l*256+j)][c*32+d] * recip_nm
          int il = row>>5, c5 = row&31, j = col>>5, d = col&31;
          int gi = ea.ic*ICH + il;
          x *= ea.recip[gi*N_DIM + j];
          ea.out_b[((size_t)(il*N_DIM + j)<<10) + (c5<<5) + d] = f2b(x);
        } else if constexpr (EPI==EPI_ZNEW) {
          size_t gp = (size_t)ea.ic*ICH_PAIR + row;
          x += ea.obias[col] + ea.addz[gp*CZ + col];
          ea.out_f[gp*CZ + col] = x;
        } else if constexpr (EPI==EPI_O) {
          // row = i, col = s_l*32+c -> o[(s_l*256+i)][h*32+c]
          int sl = col>>5, cc = col&31;
          ea.out_b[(size_t)(sl*N_DIM + row)*256 + hz*CHN + cc] = f2b(x);
        }
      }
    }
  }
}

// LayerNorm of m (fp32) with BOTH param sets -> mn_opm, mn_pwa (bf16). One wave per row of 64 ch.
__global__ __launch_bounds__(256) void ln_m_kernel(const float* __restrict__ m, const float* ow, const float* ob,
                                                   const float* pw, const float* pb,
                                                   u16* __restrict__ mo, u16* __restrict__ mp)
{
  int row  = blockIdx.x*4 + (threadIdx.x>>6);
  int lane = threadIdx.x & 63;
  float x = m[(size_t)row*CM + lane];
  float s = x, s2 = x*x;
  #pragma unroll
  for (int off=32; off; off>>=1){ s += __shfl_xor(s,off); s2 += __shfl_xor(s2,off); }
  float mu   = s*(1.f/64.f);
  float var  = s2*(1.f/64.f) - mu*mu;
  float rstd = rsqrtf(var + 1e-5f);
  float mn = (x-mu)*rstd;
  mo[(size_t)row*CM+lane] = f2b(mn*ow[lane] + ob[lane]);
  mp[(size_t)row*CM+lane] = f2b(mn*pw[lane] + pb[lane]);
}

// Convert all GEMM weight operands fp32 -> bf16 arena (incl. a_w/b_w pack).
// Layout: [0,4096) w_ab | [4096,135168) opm_o_w | [135168,151552) pwa_m_w
//         | [151552,167936) pwa_g_w | [167936,184320) pwa_o_w
__global__ __launch_bounds__(256) void cvt_w_kernel(const float* __restrict__ aw, const float* __restrict__ bw,
                                                    const float* __restrict__ ow, const float* __restrict__ mw,
                                                    const float* __restrict__ gw, const float* __restrict__ o2w,
                                                    u16* __restrict__ wb)
{
  int e = blockIdx.x*256 + threadIdx.x;
  float v;
  if (e < 4096)        { int r = e>>6, c = e&63; v = (r<32)? aw[r*64+c] : bw[(r-32)*64+c]; }
  else if (e < 135168) { v = ow[e-4096]; }
  else if (e < 151552) { v = mw[e-135168]; }
  else if (e < 167936) { v = gw[e-151552]; }
  else                 { v = o2w[e-167936]; }
  wb[e] = f2b(v);
}

// ab[(s,i)][c0..63] -> a_t[(i*32+c)][s] (c<32), b_t[(i*32+c-32)][s]
__global__ __launch_bounds__(256) void transpose_ab_kernel(const u16* __restrict__ ab,
                                                           u16* __restrict__ a_t, u16* __restrict__ b_t)
{
  __shared__ u16 t[64][72];
  int sb = blockIdx.x, i = blockIdx.y, tid = threadIdx.x;
  for (int c = tid; c < 512; c += 256){
    int sl = c>>3, kc = c&7;
    union { uint4 v; u16 h[8]; } u;
    u.v = *reinterpret_cast<const uint4*>(ab + ((size_t)(sb*64+sl)*N_DIM + i)*64 + (kc<<3));
    #pragma unroll
    for (int k=0;k<8;k++) t[sl][kc*8+k] = u.h[k];
  }
  __syncthreads();
  for (int c = tid; c < 512; c += 256){
    int cc = c>>3, sc = c&7;
    union { uint4 v; u16 h[8]; } u;
    #pragma unroll
    for (int k=0;k<8;k++) u.h[k] = t[sc*8+k][cc];
    u16* dst = (cc < 32) ? (a_t + (size_t)(i*32+cc)*S_DIM) : (b_t + (size_t)(i*32+cc-32)*S_DIM);
    *reinterpret_cast<uint4*>(dst + sb*64 + (sc<<3)) = u.v;
  }
}

__global__ __launch_bounds__(256) void num_mask_kernel(const float* __restrict__ msa, float* __restrict__ recip){
  int i = blockIdx.x, j = threadIdx.x;
  float s = 0.f;
  #pragma unroll 8
  for (int t=0;t<S_DIM;t++) s += msa[t*N_DIM+i] * msa[t*N_DIM+j];
  recip[i*N_DIM + j] = 1.f / fmaxf(s, 1.f);
}

// LN(z_new[128]) fp32 -> bias[h][pair] = dot(zn, z_w[h]) + (1-pm)*(-1e6)
__global__ __launch_bounds__(256) void ln_bias_kernel(const float* __restrict__ z_new, const float* zw, const float* zb,
                                                      const float* zwh, const float* pm, float* __restrict__ bias)
{
  int p    = blockIdx.x*4 + (threadIdx.x>>6);
  int lane = threadIdx.x & 63;
  const float* zr = z_new + (size_t)p*CZ;
  float x0 = zr[lane*2], x1 = zr[lane*2+1];
  float s = x0+x1, s2 = x0*x0 + x1*x1;
  #pragma unroll
  for (int off=32; off; off>>=1){ s += __shfl_xor(s,off); s2 += __shfl_xor(s2,off); }
  float mu   = s*(1.f/128.f);
  float var  = s2*(1.f/128.f) - mu*mu;
  float rstd = rsqrtf(var + 1e-5f);
  float zn0 = (x0-mu)*rstd*zw[lane*2]   + zb[lane*2];
  float zn1 = (x1-mu)*rstd*zw[lane*2+1] + zb[lane*2+1];
  float bm = (1.f - pm[p]) * (-1.0e6f);
  float outv = 0.f;
  #pragma unroll
  for (int hh=0; hh<8; hh++){
    float tp = zn0*zwh[hh*CZ + lane*2] + zn1*zwh[hh*CZ + lane*2+1];
    #pragma unroll
    for (int off=32; off; off>>=1) tp += __shfl_xor(tp,off);
    if (lane == hh) outv = tp + bm;
  }
  if (lane < 8) bias[(size_t)lane*NPAIR + p] = outv;
}

__global__ __launch_bounds__(256) void softmax_kernel(const float* __restrict__ bias, u16* __restrict__ w_sm){
  int r    = blockIdx.x*4 + (threadIdx.x>>6);   // r = h*256 + i
  int lane = threadIdx.x & 63;
  const float* src = bias + (size_t)(r>>8)*NPAIR + (size_t)(r&255)*N_DIM;
  float4 xv = *reinterpret_cast<const float4*>(src + lane*4);
  float mx = fmaxf(fmaxf(xv.x,xv.y), fmaxf(xv.z,xv.w));
  #pragma unroll
  for (int off=32; off; off>>=1) mx = fmaxf(mx, __shfl_xor(mx,off));
  float e0 = __expf(xv.x-mx), e1 = __expf(xv.y-mx), e2 = __expf(xv.z-mx), e3 = __expf(xv.w-mx);
  float s = e0+e1+e2+e3;
  #pragma unroll
  for (int off=32; off; off>>=1) s += __shfl_xor(s,off);
  float rs = 1.f/s;
  ushort4 st; st.x=f2b(e0*rs); st.y=f2b(e1*rs); st.z=f2b(e2*rs); st.w=f2b(e3*rs);
  *reinterpret_cast<ushort4*>(w_sm + (size_t)r*N_DIM + lane*4) = st;
}

__global__ void mult_kernel(const u16* __restrict__ g, const u16* __restrict__ o, u16* __restrict__ go, int n8){
  int idx = blockIdx.x*256 + threadIdx.x;
  if (idx < n8){
    size_t base = (size_t)idx*8;
    union { uint4 v; u16 h[8]; } a,b,c;
    a.v = *reinterpret_cast<const uint4*>(g+base);
    b.v = *reinterpret_cast<const uint4*>(o+base);
    #pragma unroll
    for (int k=0;k<8;k++) c.h[k] = f2b(b2f(a.h[k])*b2f(b.h[k]));
    *reinterpret_cast<uint4*>(go+base) = c.v;
  }
}

extern "C" void kernel_launch(void* const* d_in, const int* in_sizes, int n_in,
                              void* d_out, int out_size, void* d_ws, size_t ws_size,
                              hipStream_t stream)
{
  const float* m      = (const float*)d_in[0];
  const float* z      = (const float*)d_in[1];
  const float* msa    = (const float*)d_in[2];
  const float* pmask  = (const float*)d_in[3];
  const float* opm_nw = (const float*)d_in[4];
  const float* opm_nb = (const float*)d_in[5];
  const float* opm_aw = (const float*)d_in[6];
  const float* opm_bw = (const float*)d_in[7];
  const float* opm_ow = (const float*)d_in[8];
  const float* opm_ob = (const float*)d_in[9];
  const float* pwa_nmw= (const float*)d_in[10];
  const float* pwa_nmb= (const float*)d_in[11];
  const float* pwa_nzw= (const float*)d_in[12];
  const float* pwa_nzb= (const float*)d_in[13];
  const float* pwa_mw = (const float*)d_in[14];
  const float* pwa_gw = (const float*)d_in[15];
  const float* pwa_zw = (const float*)d_in[16];
  const float* pwa_ow = (const float*)d_in[17];
  float* out = (float*)d_out;
  char* ws = (char*)d_ws;

  // ws arenas (bytes); stage-B buffers overlay stage-A dead regions. Peak ~132 MB (validated: round-1 ran).
  u16*  mn_pwa = (u16*)(ws + 0);            // 16 MB, whole run
  u16*  mn_opm = (u16*)(ws + 16777216);     // 16 MB, dead after G1
  u16*  ab     = (u16*)(ws + 33554432);     // 16 MB, dead after transpose
  u16*  a_t    = (u16*)(ws + 50331648);     //  8 MB, dead after zt GEMMs
  u16*  b_t    = (u16*)(ws + 58720256);     //  8 MB, dead after zt GEMMs
  float* z_new = (float*)(ws + 67108864);   // 32 MB fp32, dead after ln_bias
  u16*  ztp    = (u16*)(ws + 100663296);    // 32 MB chunk scratch
  float* bias  = (float*)(ws + 134217728);  //  2 MB
  u16*  w_sm   = (u16*)(ws + 136314880);    //  1 MB
  float* recip = (float*)(ws + 137363456);  // 256 KB
  u16*  wb     = (u16*)(ws + 137625600);    // 360 KB bf16 weights arena
  u16*  v_t  = mn_opm;   // 16 MB chunk
  u16*  gbuf = ab;       // 16 MB chunk
  u16*  obuf = a_t;      // 16 MB chunk (spans a_t+b_t)
  u16*  go   = ztp;      // 16 MB chunk

  const u16* w_ab     = wb;
  const u16* opm_ow_b = wb + 4096;
  const u16* mw_b     = wb + 135168;
  const u16* gw_b     = wb + 151552;
  const u16* ow_b     = wb + 167936;

  // ---- stage A: OPM path
  ln_m_kernel<<<dim3(NPOS/4),256,0,stream>>>(m, opm_nw, opm_nb, pwa_nmw, pwa_nmb, mn_opm, mn_pwa);
  cvt_w_kernel<<<dim3(184320/256),256,0,stream>>>(opm_aw, opm_bw, opm_ow, pwa_mw, pwa_gw, pwa_ow, wb);
  { EpiArgs ea{}; ea.rowscale = msa; ea.out_b = ab; ea.ldc = 64;
    gemm_k<256,64,4,1,EPI_ROWSCALE><<<dim3(1,NPOS/256),256,0,stream>>>(mn_opm, w_ab, 64, 0,0, ea); }
  transpose_ab_kernel<<<dim3(8,256),256,0,stream>>>(ab, a_t, b_t);
  num_mask_kernel<<<dim3(256),256,0,stream>>>(msa, recip);
  for (int ic=0; ic<4; ++ic){
    { EpiArgs ea{}; ea.recip = recip; ea.out_b = ztp; ea.ic = ic;
      gemm_k<128,128,2,2,EPI_ZTP><<<dim3(64,16),256,0,stream>>>(a_t + (size_t)ic*ICH_ROWS*S_DIM, b_t, S_DIM, 0,0, ea); }
    { EpiArgs ea{}; ea.obias = opm_ob; ea.addz = z; ea.out_f = z_new; ea.ic = ic;
      gemm_k<128,128,2,2,EPI_ZNEW><<<dim3(1,ICH_PAIR/128),256,0,stream>>>(ztp, opm_ow_b, 1024, 0,0, ea); }
  }
  ln_bias_kernel<<<dim3(NPAIR/4),256,0,stream>>>(z_new, pwa_nzw, pwa_nzb, pwa_zw, pmask, bias);
  softmax_kernel<<<dim3(2048/4),256,0,stream>>>(bias, w_sm);

  // ---- stage B: PWA, s-chunked x4
  for (int sc=0; sc<4; ++sc){
    const u16* mnp = mn_pwa + (size_t)sc*CHPOS*CM;
    { EpiArgs ea{}; ea.out_b = v_t;
      gemm_k<128,128,2,2,EPI_VT><<<dim3(2,CHPOS/128),256,0,stream>>>(mnp, mw_b, 64, 0,0, ea); }
    { EpiArgs ea{}; ea.out_b = gbuf; ea.ldc = 256;
      gemm_k<128,128,2,2,EPI_SIGMOID><<<dim3(2,CHPOS/128),256,0,stream>>>(mnp, gw_b, 64, 0,0, ea); }
    { EpiArgs ea{}; ea.out_b = obuf;
      gemm_k<128,128,2,2,EPI_O><<<dim3((CHS*CHN)/128, 2, NH),256,0,stream>>>(w_sm, v_t, 256,
            (size_t)NPAIR, (size_t)(CHS*CHN)*N_DIM, ea); }
    mult_kernel<<<dim3(CHPOS*256/(256*8)),256,0,stream>>>(gbuf, obuf, go, CHPOS*256/8);
    { EpiArgs ea{}; ea.out_f = out + (size_t)sc*CHPOS*CM; ea.ldc = 64;
      gemm_k<256,64,4,1,EPI_PLAIN><<<dim3(1,CHPOS/256),256,0,stream>>>(go, ow_b, 256, 0,0, ea); }
  }
}

// Round 4
// 833.795 us; speedup vs baseline: 1.2094x; 1.2094x over previous
//
#include <hip/hip_runtime.h>
#include <stdint.h>

using u16 = unsigned short;
using u32 = unsigned int;

#define S_DIM 512
#define N_DIM 256
#define CM 64
#define CZ 128
#define NH 8
#define NPOS (S_DIM*N_DIM)       // 131072 positions (s,n)
#define NPAIR (N_DIM*N_DIM)      // 65536 pairs (i,j)
#define CHS 256                  // s-chunk (2 chunks)
#define CHPOS (CHS*N_DIM)        // 65536

__device__ __forceinline__ float b2f(u16 h){ u32 u = ((u32)h)<<16; float f; __builtin_memcpy(&f,&u,4); return f; }
__device__ __forceinline__ u16 f2b(float f){ u32 u; __builtin_memcpy(&u,&f,4); u32 r = (u + 0x7fffu + ((u>>16)&1u))>>16; return (u16)r; }

typedef __bf16 bf16_t;
typedef bf16_t bf16x8 __attribute__((ext_vector_type(8)));
typedef float  f32x4  __attribute__((ext_vector_type(4)));

__device__ __forceinline__ uint4 bfmul8(uint4 a, uint4 b){
  union{uint4 v; u16 h[8];} x,y,r;
  x.v=a; y.v=b;
  #pragma unroll
  for (int k=0;k<8;k++) r.h[k] = f2b(b2f(x.h[k])*b2f(y.h[k]));
  return r.v;
}

struct EpiArgs {
  const float* rowscale;
  u16*  out_b;
  float* out_f;
  int ldc;
};

constexpr int EPI_PLAIN=0, EPI_ROWSCALE=1, EPI_SIGMOID=2, EPI_VT=3, EPI_O=6;

// C[M,N] = A[M,K] * W[N,K]^T, bf16 in, fp32 accum. BK=64.
// WR*WC waves (=4); wave tile = FM*16 x FN*16. BM=WR*FM*16, BN=WC*FN*16.
template<int BM,int BN,int WR,int WC,int FM,int FN,int EPI,bool MULA=false>
__global__ __launch_bounds__(256) void gemm_k(const u16* __restrict__ A, const u16* __restrict__ A2,
                                              const u16* __restrict__ W,
                                              int K, size_t sAz, size_t sWz, EpiArgs ea)
{
  static_assert(BM==WR*FM*16 && BN==WC*FN*16 && WR*WC==4, "geom");
  __shared__ __align__(16) u16 lsA[BM*64];
  __shared__ __align__(16) u16 lsW[BN*64];
  const int tid  = threadIdx.x;
  const int lane = tid & 63;
  const int wv   = tid >> 6;
  const int wr   = wv / WC;
  const int wc   = wv % WC;
  const int m0   = blockIdx.y * BM;
  const int n0   = blockIdx.x * BN;
  const u16* Ab  = A  + (size_t)blockIdx.z * sAz + (size_t)m0 * K;
  const u16* A2b = MULA ? (A2 + (size_t)blockIdx.z * sAz + (size_t)m0 * K) : nullptr;
  const u16* Wb  = W  + (size_t)blockIdx.z * sWz + (size_t)n0 * K;

  f32x4 acc[FM][FN];
  #pragma unroll
  for (int i=0;i<FM;i++)
    #pragma unroll
    for (int j=0;j<FN;j++) acc[i][j] = (f32x4){0.f,0.f,0.f,0.f};

  const int nkt = K >> 6;
  for (int kt = 0; kt < nkt; ++kt) {
    for (int c = tid; c < (BM+BN)*8; c += 256) {
      if (c < BM*8) {
        int row = c>>3, kc = c&7;
        size_t off = (size_t)row*K + (kt<<6) + (kc<<3);
        uint4 v = *reinterpret_cast<const uint4*>(Ab + off);
        if constexpr (MULA) {
          uint4 v2 = *reinterpret_cast<const uint4*>(A2b + off);
          v = bfmul8(v, v2);
        }
        *reinterpret_cast<uint4*>((char*)lsA + row*128 + ((kc<<4) ^ ((row&7)<<4))) = v;
      } else {
        int c2 = c - BM*8; int row = c2>>3, kc = c2&7;
        uint4 v = *reinterpret_cast<const uint4*>(Wb + (size_t)row*K + (kt<<6) + (kc<<3));
        *reinterpret_cast<uint4*>((char*)lsW + row*128 + ((kc<<4) ^ ((row&7)<<4))) = v;
      }
    }
    __syncthreads();
    #pragma unroll
    for (int kk=0; kk<2; ++kk) {
      const int kb = (kk<<6) + ((lane>>4)<<4);
      bf16x8 af[FM], wf[FN];
      #pragma unroll
      for (int mf=0;mf<FM;mf++){
        int row = wr*FM*16 + mf*16 + (lane&15);
        af[mf] = *reinterpret_cast<const bf16x8*>((char*)lsA + row*128 + (kb ^ ((row&7)<<4)));
      }
      #pragma unroll
      for (int nf=0;nf<FN;nf++){
        int row = wc*FN*16 + nf*16 + (lane&15);
        wf[nf] = *reinterpret_cast<const bf16x8*>((char*)lsW + row*128 + (kb ^ ((row&7)<<4)));
      }
      #pragma unroll
      for (int mf=0;mf<FM;mf++)
        #pragma unroll
        for (int nf=0;nf<FN;nf++)
          acc[mf][nf] = __builtin_amdgcn_mfma_f32_16x16x32_bf16(af[mf], wf[nf], acc[mf][nf], 0,0,0);
    }
    __syncthreads();
  }

  const int hz = blockIdx.z;
  #pragma unroll
  for (int mf=0;mf<FM;mf++){
    #pragma unroll
    for (int nf=0;nf<FN;nf++){
      f32x4 v = acc[mf][nf];
      int col   = n0 + wc*FN*16 + nf*16 + (lane&15);
      int rbase = m0 + wr*FM*16 + mf*16 + ((lane>>4)<<2);
      #pragma unroll
      for (int r=0;r<4;r++){
        int row = rbase + r;
        float x = v[r];
        if constexpr (EPI==EPI_PLAIN) {
          ea.out_f[(size_t)row*ea.ldc + col] = x;
        } else if constexpr (EPI==EPI_ROWSCALE) {
          x *= ea.rowscale[row];
          ea.out_b[(size_t)row*ea.ldc + col] = f2b(x);
        } else if constexpr (EPI==EPI_SIGMOID) {
          x = 1.f/(1.f+__expf(-x));
          ea.out_b[(size_t)row*ea.ldc + col] = f2b(x);
        } else if constexpr (EPI==EPI_VT) {
          // row = s_l*256 + j ; col = h*32+c  ->  v_t[h][(s_l*32+c)][j]
          int hh = col>>5, cc = col&31, sl = row>>8, j = row&255;
          ea.out_b[((size_t)(hh*(CHS*32) + sl*32 + cc))*N_DIM + j] = f2b(x);
        } else if constexpr (EPI==EPI_O) {
          // row = i, col = s_l*32+c -> o[(s_l*256+i)][h*32+c]
          int sl = col>>5, cc = col&31;
          ea.out_b[(size_t)(sl*N_DIM + row)*256 + hz*32 + cc] = f2b(x);
        }
      }
    }
  }
}

// ---- Fused OuterProductMean: per block, zt tile for 16 (i,j) pairs -> LDS -> x o_w -> z_new.
// grid (64 j-blocks, 64 i-blocks), 4 waves (2x2).
// zt LDS layout: [p(16)][drow(32)][c(32)] bf16, with per-pair d-row ROTATION (bank spread, in-bounds):
//   byte(p,d,c) = p*2048 + ((d+p)&31)*64 + ((c*2) ^ (((d>>1)&3)<<4))
// (sw1 uses LOGICAL d on both write and read sides; mapping bijective, max byte 32767.)
// o_w is PRE-PERMUTED d-major: owp[z][d*32+c].
__global__ __launch_bounds__(256) void opm_fused(const u16* __restrict__ a_t, const u16* __restrict__ b_t,
                                                 const float* __restrict__ recip, const u16* __restrict__ owp,
                                                 const float* __restrict__ obias, const float* __restrict__ z,
                                                 float* __restrict__ z_new)
{
  __shared__ __align__(16) u16 ls[16384];    // 32 KB: stage1 A(16K)+W(16K); stage2 o_w tile [128][128k']
  __shared__ __align__(16) u16 zt[16384];    // 32 KB
  const int tid = threadIdx.x, lane = tid&63, wv = tid>>6;
  const int wr = wv>>1, wc = wv&1;
  const int bx = blockIdx.x, by = blockIdx.y;
  const u16* Ab = a_t + (size_t)by*128*S_DIM;
  const u16* Wb = b_t + (size_t)bx*128*S_DIM;
  u16* lsA = ls;
  u16* lsW = ls + 8192;

  f32x4 acc[4][4];
  #pragma unroll
  for (int i=0;i<4;i++)
    #pragma unroll
    for (int j=0;j<4;j++) acc[i][j] = (f32x4){0.f,0.f,0.f,0.f};

  // ---- stage 1: zt_tile[128(ii,c)][128(jj,d)] = A(128xK) * B(128xK)^T, K=512
  for (int kt = 0; kt < 8; ++kt) {
    for (int c = tid; c < 2048; c += 256) {
      if (c < 1024) {
        int row = c>>3, kc = c&7;
        uint4 v = *reinterpret_cast<const uint4*>(Ab + (size_t)row*S_DIM + (kt<<6) + (kc<<3));
        *reinterpret_cast<uint4*>((char*)lsA + row*128 + ((kc<<4) ^ ((row&7)<<4))) = v;
      } else {
        int c2 = c-1024; int row = c2>>3, kc = c2&7;
        uint4 v = *reinterpret_cast<const uint4*>(Wb + (size_t)row*S_DIM + (kt<<6) + (kc<<3));
        *reinterpret_cast<uint4*>((char*)lsW + row*128 + ((kc<<4) ^ ((row&7)<<4))) = v;
      }
    }
    __syncthreads();
    #pragma unroll
    for (int kk=0; kk<2; ++kk) {
      const int kb = (kk<<6) + ((lane>>4)<<4);
      bf16x8 af[4], wf[4];
      #pragma unroll
      for (int mf=0;mf<4;mf++){
        int row = wr*64 + mf*16 + (lane&15);
        af[mf] = *reinterpret_cast<const bf16x8*>((char*)lsA + row*128 + (kb ^ ((row&7)<<4)));
      }
      #pragma unroll
      for (int nf=0;nf<4;nf++){
        int row = wc*64 + nf*16 + (lane&15);
        wf[nf] = *reinterpret_cast<const bf16x8*>((char*)lsW + row*128 + (kb ^ ((row&7)<<4)));
      }
      #pragma unroll
      for (int mf=0;mf<4;mf++)
        #pragma unroll
        for (int nf=0;nf<4;nf++)
          acc[mf][nf] = __builtin_amdgcn_mfma_f32_16x16x32_bf16(af[mf], wf[nf], acc[mf][nf], 0,0,0);
    }
    __syncthreads();
  }

  // ---- epilogue 1: acc -> zt LDS (bf16, * recip), b64 per frag
  #pragma unroll
  for (int mf=0;mf<4;mf++){
    #pragma unroll
    for (int nf=0;nf<4;nf++){
      int ii = 2*wr + (mf>>1);
      int jj = 2*wc + (nf>>1);
      int p  = ii*4 + jj;
      int d  = ((nf&1)<<4) + (lane&15);
      int c0 = ((mf&1)<<4) + ((lane>>4)<<2);
      float rv = recip[(by*4+ii)*N_DIM + bx*4 + jj];
      f32x4 v = acc[mf][nf];
      union { uint2 u; u16 h[4]; } pk;
      #pragma unroll
      for (int r=0;r<4;r++) pk.h[r] = f2b(v[r]*rv);
      int byte = p*2048 + (((d + p)&31)<<6) + ((c0*2) ^ (((d>>1)&3)<<4));
      *reinterpret_cast<uint2*>((char*)zt + byte) = pk.u;
    }
  }
  __syncthreads();

  // ---- stage 2: z_opm[16 pairs][128 z] = zt[16][1024 k'] * owp[128 z][1024 k']^T
  // 8 iterations x 128 k' (= 4 d's). ls reused as [128 z][256 B] tile, reg-prefetched.
  f32x4 acc2[2] = {(f32x4){0,0,0,0},(f32x4){0,0,0,0}};
  uint4 rg[8];
  {
    #pragma unroll
    for (int j=0;j<8;j++){
      int c = tid + j*256;                 // c in [0,2048): row = c>>4, kc = c&15
      int row = c>>4, kc = c&15;
      rg[j] = *reinterpret_cast<const uint4*>(owp + (size_t)row*1024 + 0*128 + (kc<<3));
    }
  }
  for (int it=0; it<8; ++it){
    __syncthreads();   // ls free
    #pragma unroll
    for (int j=0;j<8;j++){
      int c = tid + j*256;
      int row = c>>4, kc = c&15;
      *reinterpret_cast<uint4*>((char*)ls + row*256 + ((kc<<4) ^ ((row&7)<<4))) = rg[j];
    }
    if (it<7){
      #pragma unroll
      for (int j=0;j<8;j++){
        int c = tid + j*256;
        int row = c>>4, kc = c&15;
        rg[j] = *reinterpret_cast<const uint4*>(owp + (size_t)row*1024 + (size_t)(it+1)*128 + (kc<<3));
      }
    }
    __syncthreads();   // ls ready
    #pragma unroll
    for (int kk=0; kk<4; ++kk){
      int d = it*4 + kk;
      int p  = lane&15;
      int c0 = (lane>>4)<<3;
      bf16x8 af = *reinterpret_cast<const bf16x8*>((char*)zt + p*2048 + (((d + p)&31)<<6) +
                    ((c0*2) ^ (((d>>1)&3)<<4)));
      const int kb = (kk<<6) + ((lane>>4)<<4);
      #pragma unroll
      for (int nf=0;nf<2;nf++){
        int row = wv*32 + nf*16 + (lane&15);
        bf16x8 wf = *reinterpret_cast<const bf16x8*>((char*)ls + row*256 + (kb ^ ((row&7)<<4)));
        acc2[nf] = __builtin_amdgcn_mfma_f32_16x16x32_bf16(af, wf, acc2[nf], 0,0,0);
      }
    }
  }

  // ---- epilogue 2: z_new[gp][z] = acc2 + obias + z
  #pragma unroll
  for (int nf=0;nf<2;nf++){
    int col = wv*32 + nf*16 + (lane&15);
    #pragma unroll
    for (int r=0;r<4;r++){
      int p = ((lane>>4)<<2) + r;
      size_t gp = (size_t)(by*4 + (p>>2))*N_DIM + bx*4 + (p&3);
      z_new[gp*CZ + col] = acc2[nf][r] + obias[col] + z[gp*CZ + col];
    }
  }
}

// LayerNorm of m (fp32) with BOTH param sets -> mn_opm, mn_pwa (bf16).
__global__ __launch_bounds__(256) void ln_m_kernel(const float* __restrict__ m, const float* ow, const float* ob,
                                                   const float* pw, const float* pb,
                                                   u16* __restrict__ mo, u16* __restrict__ mp)
{
  int row  = blockIdx.x*4 + (threadIdx.x>>6);
  int lane = threadIdx.x & 63;
  float x = m[(size_t)row*CM + lane];
  float s = x, s2 = x*x;
  #pragma unroll
  for (int off=32; off; off>>=1){ s += __shfl_xor(s,off); s2 += __shfl_xor(s2,off); }
  float mu   = s*(1.f/64.f);
  float var  = s2*(1.f/64.f) - mu*mu;
  float rstd = rsqrtf(var + 1e-5f);
  float mn = (x-mu)*rstd;
  mo[(size_t)row*CM+lane] = f2b(mn*ow[lane] + ob[lane]);
  mp[(size_t)row*CM+lane] = f2b(mn*pw[lane] + pb[lane]);
}

// fp32 -> bf16 weights arena. owp region is d-major permuted: wb[4096 + z*1024 + d*32 + c] = ow[z*1024 + c*32 + d]
// Layout: [0,4096) w_ab | [4096,135168) owp | [135168,151552) pwa_m_w | [151552,167936) pwa_g_w | [167936,184320) pwa_o_w
__global__ __launch_bounds__(256) void cvt_w_kernel(const float* __restrict__ aw, const float* __restrict__ bw,
                                                    const float* __restrict__ ow, const float* __restrict__ mw,
                                                    const float* __restrict__ gw, const float* __restrict__ o2w,
                                                    u16* __restrict__ wb)
{
  int e = blockIdx.x*256 + threadIdx.x;
  float v;
  if (e < 4096)        { int r = e>>6, c = e&63; v = (r<32)? aw[r*64+c] : bw[(r-32)*64+c]; }
  else if (e < 135168) { int t = e-4096; int zz = t>>10, rem = t&1023, d = rem>>5, c = rem&31;
                         v = ow[zz*1024 + c*32 + d]; }
  else if (e < 151552) { v = mw[e-135168]; }
  else if (e < 167936) { v = gw[e-151552]; }
  else                 { v = o2w[e-167936]; }
  wb[e] = f2b(v);
}

// ab[(s,i)][c0..63] -> a_t[(i*32+c)][s] (c<32), b_t[(i*32+c-32)][s]
__global__ __launch_bounds__(256) void transpose_ab_kernel(const u16* __restrict__ ab,
                                                           u16* __restrict__ a_t, u16* __restrict__ b_t)
{
  __shared__ u16 t[64][72];
  int sb = blockIdx.x, i = blockIdx.y, tid = threadIdx.x;
  for (int c = tid; c < 512; c += 256){
    int sl = c>>3, kc = c&7;
    union { uint4 v; u16 h[8]; } u;
    u.v = *reinterpret_cast<const uint4*>(ab + ((size_t)(sb*64+sl)*N_DIM + i)*64 + (kc<<3));
    #pragma unroll
    for (int k=0;k<8;k++) t[sl][kc*8+k] = u.h[k];
  }
  __syncthreads();
  for (int c = tid; c < 512; c += 256){
    int cc = c>>3, sc = c&7;
    union { uint4 v; u16 h[8]; } u;
    #pragma unroll
    for (int k=0;k<8;k++) u.h[k] = t[sc*8+k][cc];
    u16* dst = (cc < 32) ? (a_t + (size_t)(i*32+cc)*S_DIM) : (b_t + (size_t)(i*32+cc-32)*S_DIM);
    *reinterpret_cast<uint4*>(dst + sb*64 + (sc<<3)) = u.v;
  }
}

__global__ __launch_bounds__(256) void num_mask_kernel(const float* __restrict__ msa, float* __restrict__ recip){
  int i = blockIdx.x, j = threadIdx.x;
  float s = 0.f;
  #pragma unroll 8
  for (int t=0;t<S_DIM;t++) s += msa[t*N_DIM+i] * msa[t*N_DIM+j];
  recip[i*N_DIM + j] = 1.f / fmaxf(s, 1.f);
}

// LN(z_new[128]) fp32 -> bias[h][pair] = dot(zn, z_w[h]) + (1-pm)*(-1e6)
__global__ __launch_bounds__(256) void ln_bias_kernel(const float* __restrict__ z_new, const float* zw, const float* zb,
                                                      const float* zwh, const float* pm, float* __restrict__ bias)
{
  int p    = blockIdx.x*4 + (threadIdx.x>>6);
  int lane = threadIdx.x & 63;
  const float* zr = z_new + (size_t)p*CZ;
  float x0 = zr[lane*2], x1 = zr[lane*2+1];
  float s = x0+x1, s2 = x0*x0 + x1*x1;
  #pragma unroll
  for (int off=32; off; off>>=1){ s += __shfl_xor(s,off); s2 += __shfl_xor(s2,off); }
  float mu   = s*(1.f/128.f);
  float var  = s2*(1.f/128.f) - mu*mu;
  float rstd = rsqrtf(var + 1e-5f);
  float zn0 = (x0-mu)*rstd*zw[lane*2]   + zb[lane*2];
  float zn1 = (x1-mu)*rstd*zw[lane*2+1] + zb[lane*2+1];
  float bm = (1.f - pm[p]) * (-1.0e6f);
  float outv = 0.f;
  #pragma unroll
  for (int hh=0; hh<8; hh++){
    float tp = zn0*zwh[hh*CZ + lane*2] + zn1*zwh[hh*CZ + lane*2+1];
    #pragma unroll
    for (int off=32; off; off>>=1) tp += __shfl_xor(tp,off);
    if (lane == hh) outv = tp + bm;
  }
  if (lane < 8) bias[(size_t)lane*NPAIR + p] = outv;
}

__global__ __launch_bounds__(256) void softmax_kernel(const float* __restrict__ bias, u16* __restrict__ w_sm){
  int r    = blockIdx.x*4 + (threadIdx.x>>6);   // r = h*256 + i
  int lane = threadIdx.x & 63;
  const float* src = bias + (size_t)(r>>8)*NPAIR + (size_t)(r&255)*N_DIM;
  float4 xv = *reinterpret_cast<const float4*>(src + lane*4);
  float mx = fmaxf(fmaxf(xv.x,xv.y), fmaxf(xv.z,xv.w));
  #pragma unroll
  for (int off=32; off; off>>=1) mx = fmaxf(mx, __shfl_xor(mx,off));
  float e0 = __expf(xv.x-mx), e1 = __expf(xv.y-mx), e2 = __expf(xv.z-mx), e3 = __expf(xv.w-mx);
  float s = e0+e1+e2+e3;
  #pragma unroll
  for (int off=32; off; off>>=1) s += __shfl_xor(s,off);
  float rs = 1.f/s;
  ushort4 st; st.x=f2b(e0*rs); st.y=f2b(e1*rs); st.z=f2b(e2*rs); st.w=f2b(e3*rs);
  *reinterpret_cast<ushort4*>(w_sm + (size_t)r*N_DIM + lane*4) = st;
}

extern "C" void kernel_launch(void* const* d_in, const int* in_sizes, int n_in,
                              void* d_out, int out_size, void* d_ws, size_t ws_size,
                              hipStream_t stream)
{
  const float* m      = (const float*)d_in[0];
  const float* z      = (const float*)d_in[1];
  const float* msa    = (const float*)d_in[2];
  const float* pmask  = (const float*)d_in[3];
  const float* opm_nw = (const float*)d_in[4];
  const float* opm_nb = (const float*)d_in[5];
  const float* opm_aw = (const float*)d_in[6];
  const float* opm_bw = (const float*)d_in[7];
  const float* opm_ow = (const float*)d_in[8];
  const float* opm_ob = (const float*)d_in[9];
  const float* pwa_nmw= (const float*)d_in[10];
  const float* pwa_nmb= (const float*)d_in[11];
  const float* pwa_nzw= (const float*)d_in[12];
  const float* pwa_nzb= (const float*)d_in[13];
  const float* pwa_mw = (const float*)d_in[14];
  const float* pwa_gw = (const float*)d_in[15];
  const float* pwa_zw = (const float*)d_in[16];
  const float* pwa_ow = (const float*)d_in[17];
  float* out = (float*)d_out;
  char* ws = (char*)d_ws;

  // Arenas (MiB offsets). Peak 132 MiB (<138 proven).
  const size_t MB = 1024*1024;
  u16*  mn_pwa = (u16*)(ws + 0);          // [0,16) whole run
  u16*  mn_opm = (u16*)(ws + 16*MB);      // [16,32) dead after ROWSCALE
  u16*  ab     = (u16*)(ws + 32*MB);      // [32,48) dead after transpose
  u16*  a_t    = (u16*)(ws + 48*MB);      // [48,56) dead after opm_fused
  u16*  b_t    = (u16*)(ws + 56*MB);      // [56,64) dead after opm_fused
  float* z_new = (float*)(ws + 64*MB);    // [64,96) fp32, dead after ln_bias
  float* bias  = (float*)(ws + 128*MB);   // [128,130)
  u16*  w_sm   = (u16*)(ws + 130*MB);     // [130,131)
  float* recip = (float*)(ws + 131*MB);   // 256 KB
  u16*  wb     = (u16*)(ws + 131*MB + 512*1024);  // 360 KB
  // stage-B per-chunk overlays (alive only after ln_bias):
  u16*  v_t  = (u16*)(ws + 16*MB);        // 32 MiB
  u16*  gbuf = (u16*)(ws + 48*MB);        // 32 MiB
  u16*  obuf = (u16*)(ws + 80*MB);        // 32 MiB

  const u16* w_ab = wb;
  const u16* owp  = wb + 4096;
  const u16* mw_b = wb + 135168;
  const u16* gw_b = wb + 151552;
  const u16* ow_b = wb + 167936;

  // ---- stage A: OPM path
  ln_m_kernel<<<dim3(NPOS/4),256,0,stream>>>(m, opm_nw, opm_nb, pwa_nmw, pwa_nmb, mn_opm, mn_pwa);
  cvt_w_kernel<<<dim3(184320/256),256,0,stream>>>(opm_aw, opm_bw, opm_ow, pwa_mw, pwa_gw, pwa_ow, wb);
  { EpiArgs ea{}; ea.rowscale = msa; ea.out_b = ab; ea.ldc = 64;
    gemm_k<128,64,2,2,4,2,EPI_ROWSCALE><<<dim3(1,NPOS/128),256,0,stream>>>(mn_opm, nullptr, w_ab, 64, 0,0, ea); }
  transpose_ab_kernel<<<dim3(8,256),256,0,stream>>>(ab, a_t, b_t);
  num_mask_kernel<<<dim3(256),256,0,stream>>>(msa, recip);
  opm_fused<<<dim3(64,64),256,0,stream>>>(a_t, b_t, recip, owp, opm_ob, z, z_new);
  ln_bias_kernel<<<dim3(NPAIR/4),256,0,stream>>>(z_new, pwa_nzw, pwa_nzb, pwa_zw, pmask, bias);
  softmax_kernel<<<dim3(2048/4),256,0,stream>>>(bias, w_sm);

  // ---- stage B: PWA, s-chunked x2 (CHS=256)
  for (int sc=0; sc<2; ++sc){
    const u16* mnp = mn_pwa + (size_t)sc*CHPOS*CM;
    { EpiArgs ea{}; ea.out_b = v_t;
      gemm_k<128,128,2,2,4,4,EPI_VT><<<dim3(2,CHPOS/128),256,0,stream>>>(mnp, nullptr, mw_b, 64, 0,0, ea); }
    { EpiArgs ea{}; ea.out_b = gbuf; ea.ldc = 256;
      gemm_k<128,128,2,2,4,4,EPI_SIGMOID><<<dim3(2,CHPOS/128),256,0,stream>>>(mnp, nullptr, gw_b, 64, 0,0, ea); }
    { EpiArgs ea{}; ea.out_b = obuf;
      gemm_k<128,128,2,2,4,4,EPI_O><<<dim3((CHS*32)/128, 2, NH),256,0,stream>>>(w_sm, nullptr, v_t, 256,
            (size_t)NPAIR, (size_t)(CHS*32)*N_DIM, ea); }
    { EpiArgs ea{}; ea.out_f = out + (size_t)sc*CHPOS*CM; ea.ldc = 64;
      gemm_k<128,64,2,2,4,2,EPI_PLAIN,true><<<dim3(1,CHPOS/128),256,0,stream>>>(gbuf, obuf, ow_b, 256, 0,0, ea); }
  }
}

// Round 6
// 529.417 us; speedup vs baseline: 1.9047x; 1.5749x over previous
//
#include <hip/hip_runtime.h>
#include <stdint.h>

using u16 = unsigned short;
using u32 = unsigned int;

#define S_DIM 512
#define N_DIM 256
#define CM 64
#define CZ 128
#define NH 8
#define NPOS (S_DIM*N_DIM)       // 131072 positions (s,n)
#define NPAIR (N_DIM*N_DIM)      // 65536 pairs (i,j)
#define CHS 256                  // s-chunk (2 chunks)
#define CHPOS (CHS*N_DIM)        // 65536

__device__ __forceinline__ float b2f(u16 h){ u32 u = ((u32)h)<<16; float f; __builtin_memcpy(&f,&u,4); return f; }
__device__ __forceinline__ u16 f2b(float f){ u32 u; __builtin_memcpy(&u,&f,4); u32 r = (u + 0x7fffu + ((u>>16)&1u))>>16; return (u16)r; }

typedef __bf16 bf16_t;
typedef bf16_t bf16x8 __attribute__((ext_vector_type(8)));
typedef float  f32x4  __attribute__((ext_vector_type(4)));

typedef const __attribute__((address_space(1))) void* gvp;
typedef __attribute__((address_space(3))) void* lvp;
// CK-style addrspace routing through uintptr_t (direct generic->AS3 cast can fail to compile)
#define GLOAD_LDS16(g, l) __builtin_amdgcn_global_load_lds((gvp)(uintptr_t)(g), (lvp)(uintptr_t)(l), 16, 0, 0)

__device__ __forceinline__ uint4 bfmul8(uint4 a, uint4 b){
  union{uint4 v; u16 h[8];} x,y,r;
  x.v=a; y.v=b;
  #pragma unroll
  for (int k=0;k<8;k++) r.h[k] = f2b(b2f(x.h[k])*b2f(y.h[k]));
  return r.v;
}

struct EpiArgs {
  const float* rowscale;
  u16*  out_b;
  float* out_f;
  int ldc;
};

constexpr int EPI_PLAIN=0, EPI_ROWSCALE=1, EPI_SIGMOID=2, EPI_VT=3, EPI_O=6;

// C[M,N] = A[M,K] * W[N,K]^T, bf16 in, fp32 accum. BK=64.
// WR*WC waves (=4); wave tile = FM*16 x FN*16. BM=WR*FM*16, BN=WC*FN*16.
// Staging: global_load_lds width-16, swizzle baked into per-lane SOURCE addr (m173);
// MULA path (g*o fused) keeps reg-staging (needs the multiply).
template<int BM,int BN,int WR,int WC,int FM,int FN,int EPI,bool MULA=false>
__global__ __launch_bounds__(256) void gemm_k(const u16* __restrict__ A, const u16* __restrict__ A2,
                                              const u16* __restrict__ W,
                                              int K, size_t sAz, size_t sWz, EpiArgs ea)
{
  static_assert(BM==WR*FM*16 && BN==WC*FN*16 && WR*WC==4, "geom");
  __shared__ __align__(16) u16 lsA[BM*64];
  __shared__ __align__(16) u16 lsW[BN*64];
  const int tid  = threadIdx.x;
  const int lane = tid & 63;
  const int wv   = tid >> 6;
  const int wr   = wv / WC;
  const int wc   = wv % WC;
  const int m0   = blockIdx.y * BM;
  const int n0   = blockIdx.x * BN;
  const u16* Ab  = A  + (size_t)blockIdx.z * sAz + (size_t)m0 * K;
  const u16* A2b = MULA ? (A2 + (size_t)blockIdx.z * sAz + (size_t)m0 * K) : nullptr;
  const u16* Wb  = W  + (size_t)blockIdx.z * sWz + (size_t)n0 * K;

  f32x4 acc[FM][FN];
  #pragma unroll
  for (int i=0;i<FM;i++)
    #pragma unroll
    for (int j=0;j<FN;j++) acc[i][j] = (f32x4){0.f,0.f,0.f,0.f};

  const int nkt = K >> 6;
  for (int kt = 0; kt < nkt; ++kt) {
    if constexpr (!MULA) {
      #pragma unroll
      for (int c0 = 0; c0 < BM*8; c0 += 256) {
        int cc = c0 + (wv<<6) + lane;
        int row = cc>>3, kc = cc&7;
        GLOAD_LDS16(Ab + (size_t)row*K + (kt<<6) + ((kc ^ (row&7))<<3),
                    lsA + (size_t)(c0 + (wv<<6))*8);
      }
      #pragma unroll
      for (int c0 = 0; c0 < BN*8; c0 += 256) {
        int cc = c0 + (wv<<6) + lane;
        int row = cc>>3, kc = cc&7;
        GLOAD_LDS16(Wb + (size_t)row*K + (kt<<6) + ((kc ^ (row&7))<<3),
                    lsW + (size_t)(c0 + (wv<<6))*8);
      }
    } else {
      for (int c = tid; c < (BM+BN)*8; c += 256) {
        if (c < BM*8) {
          int row = c>>3, kc = c&7;
          size_t off = (size_t)row*K + (kt<<6) + (kc<<3);
          uint4 v = *reinterpret_cast<const uint4*>(Ab + off);
          uint4 v2 = *reinterpret_cast<const uint4*>(A2b + off);
          v = bfmul8(v, v2);
          *reinterpret_cast<uint4*>((char*)lsA + row*128 + ((kc<<4) ^ ((row&7)<<4))) = v;
        } else {
          int c2 = c - BM*8; int row = c2>>3, kc = c2&7;
          uint4 v = *reinterpret_cast<const uint4*>(Wb + (size_t)row*K + (kt<<6) + (kc<<3));
          *reinterpret_cast<uint4*>((char*)lsW + row*128 + ((kc<<4) ^ ((row&7)<<4))) = v;
        }
      }
    }
    __syncthreads();
    #pragma unroll
    for (int kk=0; kk<2; ++kk) {
      const int kb = (kk<<6) + ((lane>>4)<<4);
      bf16x8 af[FM], wf[FN];
      #pragma unroll
      for (int mf=0;mf<FM;mf++){
        int row = wr*FM*16 + mf*16 + (lane&15);
        af[mf] = *reinterpret_cast<const bf16x8*>((char*)lsA + row*128 + (kb ^ ((row&7)<<4)));
      }
      #pragma unroll
      for (int nf=0;nf<FN;nf++){
        int row = wc*FN*16 + nf*16 + (lane&15);
        wf[nf] = *reinterpret_cast<const bf16x8*>((char*)lsW + row*128 + (kb ^ ((row&7)<<4)));
      }
      #pragma unroll
      for (int mf=0;mf<FM;mf++)
        #pragma unroll
        for (int nf=0;nf<FN;nf++)
          acc[mf][nf] = __builtin_amdgcn_mfma_f32_16x16x32_bf16(af[mf], wf[nf], acc[mf][nf], 0,0,0);
    }
    __syncthreads();
  }

  const int hz = blockIdx.z;
  #pragma unroll
  for (int mf=0;mf<FM;mf++){
    #pragma unroll
    for (int nf=0;nf<FN;nf++){
      f32x4 v = acc[mf][nf];
      int col   = n0 + wc*FN*16 + nf*16 + (lane&15);
      int rbase = m0 + wr*FM*16 + mf*16 + ((lane>>4)<<2);
      #pragma unroll
      for (int r=0;r<4;r++){
        int row = rbase + r;
        float x = v[r];
        if constexpr (EPI==EPI_PLAIN) {
          ea.out_f[(size_t)row*ea.ldc + col] = x;
        } else if constexpr (EPI==EPI_ROWSCALE) {
          x *= ea.rowscale[row];
          ea.out_b[(size_t)row*ea.ldc + col] = f2b(x);
        } else if constexpr (EPI==EPI_SIGMOID) {
          x = 1.f/(1.f+__expf(-x));
          ea.out_b[(size_t)row*ea.ldc + col] = f2b(x);
        } else if constexpr (EPI==EPI_VT) {
          // row = s_l*256 + j ; col = h*32+c  ->  v_t[h][(s_l*32+c)][j]
          int hh = col>>5, cc = col&31, sl = row>>8, j = row&255;
          ea.out_b[((size_t)(hh*(CHS*32) + sl*32 + cc))*N_DIM + j] = f2b(x);
        } else if constexpr (EPI==EPI_O) {
          // row = i, col = s_l*32+c -> o[(s_l*256+i)][h*32+c]
          int sl = col>>5, cc = col&31;
          ea.out_b[(size_t)(sl*N_DIM + row)*256 + hz*32 + cc] = f2b(x);
        }
      }
    }
  }
}

// ---- Fused OuterProductMean. Grid: 1D 4096, XCD-bijective swizzle; 4 waves (2x2).
// Stage 1: zt tile [128(i,c)][128(j,d)] via global_load_lds (swizzle on source addr).
// Epilogue 1 -> zt LDS [p][(d+p)&31 rows][c], sw1 = ((d>>1)&3)<<4 on byte.
// Stage 2: per-wave private: wave wv needs only z-rows [32wv,32wv+32) of o_w -> 8KB slab DMA,
//          wave-local vmcnt sync, NO barriers. o_w pre-swizzled (owp_sw) so linear DMA = swizzled LDS.
__global__ __launch_bounds__(256,1) void opm_fused(const u16* __restrict__ a_t, const u16* __restrict__ b_t,
                                                   const float* __restrict__ recip, const u16* __restrict__ owp,
                                                   const float* __restrict__ obias, const float* __restrict__ z,
                                                   float* __restrict__ z_new)
{
  __shared__ __align__(16) u16 ls[16384];    // 32 KB: stage1 A(16K)+W(16K); stage2 4x 8KB wave slabs
  __shared__ __align__(16) u16 zt[16384];    // 32 KB
  const int tid = threadIdx.x, lane = tid&63, wv = tid>>6;
  const int wr = wv>>1, wc = wv&1;
  const int bid = blockIdx.x;
  const int swz = (bid&7)*512 + (bid>>3);    // bijective (4096%8==0): XCD x owns by in [8x,8x+8)
  const int by = swz>>6, bx = swz&63;
  const u16* Ab = a_t + (size_t)by*128*S_DIM;
  const u16* Wb = b_t + (size_t)bx*128*S_DIM;
  u16* lsA = ls;
  u16* lsW = ls + 8192;

  f32x4 acc[4][4];
  #pragma unroll
  for (int i=0;i<4;i++)
    #pragma unroll
    for (int j=0;j<4;j++) acc[i][j] = (f32x4){0.f,0.f,0.f,0.f};

  // ---- stage 1: zt_tile = A(128xK) * B(128xK)^T, K=512
  for (int kt = 0; kt < 8; ++kt) {
    #pragma unroll
    for (int c0 = 0; c0 < 1024; c0 += 256) {
      int cc = c0 + (wv<<6) + lane;
      int row = cc>>3, kc = cc&7;
      size_t srcoff = (size_t)row*S_DIM + (kt<<6) + ((kc ^ (row&7))<<3);
      GLOAD_LDS16(Ab + srcoff, lsA + (size_t)(c0 + (wv<<6))*8);
      GLOAD_LDS16(Wb + srcoff, lsW + (size_t)(c0 + (wv<<6))*8);
    }
    __syncthreads();
    #pragma unroll
    for (int kk=0; kk<2; ++kk) {
      const int kb = (kk<<6) + ((lane>>4)<<4);
      bf16x8 af[4], wf[4];
      #pragma unroll
      for (int mf=0;mf<4;mf++){
        int row = wr*64 + mf*16 + (lane&15);
        af[mf] = *reinterpret_cast<const bf16x8*>((char*)lsA + row*128 + (kb ^ ((row&7)<<4)));
      }
      #pragma unroll
      for (int nf=0;nf<4;nf++){
        int row = wc*64 + nf*16 + (lane&15);
        wf[nf] = *reinterpret_cast<const bf16x8*>((char*)lsW + row*128 + (kb ^ ((row&7)<<4)));
      }
      #pragma unroll
      for (int mf=0;mf<4;mf++)
        #pragma unroll
        for (int nf=0;nf<4;nf++)
          acc[mf][nf] = __builtin_amdgcn_mfma_f32_16x16x32_bf16(af[mf], wf[nf], acc[mf][nf], 0,0,0);
    }
    __syncthreads();
  }

  // ---- epilogue 1: acc -> zt LDS (bf16, * recip)
  #pragma unroll
  for (int mf=0;mf<4;mf++){
    #pragma unroll
    for (int nf=0;nf<4;nf++){
      int ii = 2*wr + (mf>>1);
      int jj = 2*wc + (nf>>1);
      int p  = ii*4 + jj;
      int d  = ((nf&1)<<4) + (lane&15);
      int c0 = ((mf&1)<<4) + ((lane>>4)<<2);
      float rv = recip[(by*4+ii)*N_DIM + bx*4 + jj];
      f32x4 v = acc[mf][nf];
      union { uint2 u; u16 h[4]; } pk;
      #pragma unroll
      for (int r=0;r<4;r++) pk.h[r] = f2b(v[r]*rv);
      int byte = p*2048 + (((d + p)&31)<<6) + ((c0*2) ^ (((d>>1)&3)<<4));
      *reinterpret_cast<uint2*>((char*)zt + byte) = pk.u;
    }
  }
  __syncthreads();

  // ---- stage 2: z_opm[16 pairs][128 z] = zt[16][1024 k'] * owp[128 z][1024 k']^T
  // Wave-private: wave wv reads only z-rows [32wv, 32wv+32).
  f32x4 acc2[2] = {(f32x4){0,0,0,0},(f32x4){0,0,0,0}};
  u16* lsw2 = ls + wv*4096;             // 8 KB slab
  const u16* owpw = owp + wv*4096;      // rows [32wv..) within each 16K-u16 tile
  for (int it=0; it<8; ++it){
    #pragma unroll
    for (int j=0;j<8;j++)
      GLOAD_LDS16(owpw + (size_t)it*16384 + j*512 + lane*8, lsw2 + j*512);
    asm volatile("s_waitcnt vmcnt(0)" ::: "memory");
    __builtin_amdgcn_sched_barrier(0);
    #pragma unroll
    for (int kk=0; kk<4; ++kk){
      int d = it*4 + kk;
      int p  = lane&15;
      int c0 = (lane>>4)<<3;
      bf16x8 af = *reinterpret_cast<const bf16x8*>((char*)zt + p*2048 + (((d + p)&31)<<6) +
                    ((c0*2) ^ (((d>>1)&3)<<4)));
      const int kb = (kk<<6) + ((lane>>4)<<4);
      #pragma unroll
      for (int nf=0;nf<2;nf++){
        int rl = nf*16 + (lane&15);
        bf16x8 wf = *reinterpret_cast<const bf16x8*>((char*)lsw2 + rl*256 + (kb ^ ((rl&7)<<4)));
        acc2[nf] = __builtin_amdgcn_mfma_f32_16x16x32_bf16(af, wf, acc2[nf], 0,0,0);
      }
    }
    __builtin_amdgcn_sched_barrier(0);
  }

  // ---- epilogue 2: z_new[gp][z] = acc2 + obias + z
  #pragma unroll
  for (int nf=0;nf<2;nf++){
    int col = wv*32 + nf*16 + (lane&15);
    #pragma unroll
    for (int r=0;r<4;r++){
      int p = ((lane>>4)<<2) + r;
      size_t gp = (size_t)(by*4 + (p>>2))*N_DIM + bx*4 + (p&3);
      z_new[gp*CZ + col] = acc2[nf][r] + obias[col] + z[gp*CZ + col];
    }
  }
}

// LayerNorm of m (fp32) with BOTH param sets -> mn_opm, mn_pwa (bf16).
__global__ __launch_bounds__(256) void ln_m_kernel(const float* __restrict__ m, const float* ow, const float* ob,
                                                   const float* pw, const float* pb,
                                                   u16* __restrict__ mo, u16* __restrict__ mp)
{
  int row  = blockIdx.x*4 + (threadIdx.x>>6);
  int lane = threadIdx.x & 63;
  float x = m[(size_t)row*CM + lane];
  float s = x, s2 = x*x;
  #pragma unroll
  for (int off=32; off; off>>=1){ s += __shfl_xor(s,off); s2 += __shfl_xor(s2,off); }
  float mu   = s*(1.f/64.f);
  float var  = s2*(1.f/64.f) - mu*mu;
  float rstd = rsqrtf(var + 1e-5f);
  float mn = (x-mu)*rstd;
  mo[(size_t)row*CM+lane] = f2b(mn*ow[lane] + ob[lane]);
  mp[(size_t)row*CM+lane] = f2b(mn*pw[lane] + pb[lane]);
}

// fp32 -> bf16 weights arena.
// owp region stores PHYSICAL order for stage-2 DMA: t = it*16384 + row*128 + h_phys,
//   k_loc = h_phys ^ ((row&7)<<3); k' = it*128 + k_loc; d = k'>>5, c = k'&31; v = ow[row][c*32+d].
// Layout: [0,4096) w_ab | [4096,135168) owp_sw | [135168,151552) pwa_m_w | [151552,167936) pwa_g_w | [167936,184320) pwa_o_w
__global__ __launch_bounds__(256) void cvt_w_kernel(const float* __restrict__ aw, const float* __restrict__ bw,
                                                    const float* __restrict__ ow, const float* __restrict__ mw,
                                                    const float* __restrict__ gw, const float* __restrict__ o2w,
                                                    u16* __restrict__ wb)
{
  int e = blockIdx.x*256 + threadIdx.x;
  float v;
  if (e < 4096)        { int r = e>>6, c = e&63; v = (r<32)? aw[r*64+c] : bw[(r-32)*64+c]; }
  else if (e < 135168) { int t = e-4096; int it = t>>14, rem = t&16383, row = rem>>7, h = rem&127;
                         int kl = h ^ ((row&7)<<3);
                         int kp = it*128 + kl;
                         int d = kp>>5, c = kp&31;
                         v = ow[row*1024 + c*32 + d]; }
  else if (e < 151552) { v = mw[e-135168]; }
  else if (e < 167936) { v = gw[e-151552]; }
  else                 { v = o2w[e-167936]; }
  wb[e] = f2b(v);
}

// ab[(s,i)][c0..63] -> a_t[(i*32+c)][s] (c<32), b_t[(i*32+c-32)][s]
__global__ __launch_bounds__(256) void transpose_ab_kernel(const u16* __restrict__ ab,
                                                           u16* __restrict__ a_t, u16* __restrict__ b_t)
{
  __shared__ u16 t[64][72];
  int sb = blockIdx.x, i = blockIdx.y, tid = threadIdx.x;
  for (int c = tid; c < 512; c += 256){
    int sl = c>>3, kc = c&7;
    union { uint4 v; u16 h[8]; } u;
    u.v = *reinterpret_cast<const uint4*>(ab + ((size_t)(sb*64+sl)*N_DIM + i)*64 + (kc<<3));
    #pragma unroll
    for (int k=0;k<8;k++) t[sl][kc*8+k] = u.h[k];
  }
  __syncthreads();
  for (int c = tid; c < 512; c += 256){
    int cc = c>>3, sc = c&7;
    union { uint4 v; u16 h[8]; } u;
    #pragma unroll
    for (int k=0;k<8;k++) u.h[k] = t[sc*8+k][cc];
    u16* dst = (cc < 32) ? (a_t + (size_t)(i*32+cc)*S_DIM) : (b_t + (size_t)(i*32+cc-32)*S_DIM);
    *reinterpret_cast<uint4*>(dst + sb*64 + (sc<<3)) = u.v;
  }
}

__global__ __launch_bounds__(256) void num_mask_kernel(const float* __restrict__ msa, float* __restrict__ recip){
  int i = blockIdx.x, j = threadIdx.x;
  float s = 0.f;
  #pragma unroll 8
  for (int t=0;t<S_DIM;t++) s += msa[t*N_DIM+i] * msa[t*N_DIM+j];
  recip[i*N_DIM + j] = 1.f / fmaxf(s, 1.f);
}

// LN(z_new[128]) fp32 -> bias[h][pair] = dot(zn, z_w[h]) + (1-pm)*(-1e6)
__global__ __launch_bounds__(256) void ln_bias_kernel(const float* __restrict__ z_new, const float* zw, const float* zb,
                                                      const float* zwh, const float* pm, float* __restrict__ bias)
{
  int p    = blockIdx.x*4 + (threadIdx.x>>6);
  int lane = threadIdx.x & 63;
  const float* zr = z_new + (size_t)p*CZ;
  float x0 = zr[lane*2], x1 = zr[lane*2+1];
  float s = x0+x1, s2 = x0*x0 + x1*x1;
  #pragma unroll
  for (int off=32; off; off>>=1){ s += __shfl_xor(s,off); s2 += __shfl_xor(s2,off); }
  float mu   = s*(1.f/128.f);
  float var  = s2*(1.f/128.f) - mu*mu;
  float rstd = rsqrtf(var + 1e-5f);
  float zn0 = (x0-mu)*rstd*zw[lane*2]   + zb[lane*2];
  float zn1 = (x1-mu)*rstd*zw[lane*2+1] + zb[lane*2+1];
  float bm = (1.f - pm[p]) * (-1.0e6f);
  float outv = 0.f;
  #pragma unroll
  for (int hh=0; hh<8; hh++){
    float tp = zn0*zwh[hh*CZ + lane*2] + zn1*zwh[hh*CZ + lane*2+1];
    #pragma unroll
    for (int off=32; off; off>>=1) tp += __shfl_xor(tp,off);
    if (lane == hh) outv = tp + bm;
  }
  if (lane < 8) bias[(size_t)lane*NPAIR + p] = outv;
}

__global__ __launch_bounds__(256) void softmax_kernel(const float* __restrict__ bias, u16* __restrict__ w_sm){
  int r    = blockIdx.x*4 + (threadIdx.x>>6);   // r = h*256 + i
  int lane = threadIdx.x & 63;
  const float* src = bias + (size_t)(r>>8)*NPAIR + (size_t)(r&255)*N_DIM;
  float4 xv = *reinterpret_cast<const float4*>(src + lane*4);
  float mx = fmaxf(fmaxf(xv.x,xv.y), fmaxf(xv.z,xv.w));
  #pragma unroll
  for (int off=32; off; off>>=1) mx = fmaxf(mx, __shfl_xor(mx,off));
  float e0 = __expf(xv.x-mx), e1 = __expf(xv.y-mx), e2 = __expf(xv.z-mx), e3 = __expf(xv.w-mx);
  float s = e0+e1+e2+e3;
  #pragma unroll
  for (int off=32; off; off>>=1) s += __shfl_xor(s,off);
  float rs = 1.f/s;
  ushort4 st; st.x=f2b(e0*rs); st.y=f2b(e1*rs); st.z=f2b(e2*rs); st.w=f2b(e3*rs);
  *reinterpret_cast<ushort4*>(w_sm + (size_t)r*N_DIM + lane*4) = st;
}

extern "C" void kernel_launch(void* const* d_in, const int* in_sizes, int n_in,
                              void* d_out, int out_size, void* d_ws, size_t ws_size,
                              hipStream_t stream)
{
  const float* m      = (const float*)d_in[0];
  const float* z      = (const float*)d_in[1];
  const float* msa    = (const float*)d_in[2];
  const float* pmask  = (const float*)d_in[3];
  const float* opm_nw = (const float*)d_in[4];
  const float* opm_nb = (const float*)d_in[5];
  const float* opm_aw = (const float*)d_in[6];
  const float* opm_bw = (const float*)d_in[7];
  const float* opm_ow = (const float*)d_in[8];
  const float* opm_ob = (const float*)d_in[9];
  const float* pwa_nmw= (const float*)d_in[10];
  const float* pwa_nmb= (const float*)d_in[11];
  const float* pwa_nzw= (const float*)d_in[12];
  const float* pwa_nzb= (const float*)d_in[13];
  const float* pwa_mw = (const float*)d_in[14];
  const float* pwa_gw = (const float*)d_in[15];
  const float* pwa_zw = (const float*)d_in[16];
  const float* pwa_ow = (const float*)d_in[17];
  float* out = (float*)d_out;
  char* ws = (char*)d_ws;

  // Arenas (MiB offsets). Peak 132 MiB.
  const size_t MB = 1024*1024;
  u16*  mn_pwa = (u16*)(ws + 0);          // [0,16) whole run
  u16*  mn_opm = (u16*)(ws + 16*MB);      // [16,32) dead after ROWSCALE
  u16*  ab     = (u16*)(ws + 32*MB);      // [32,48) dead after transpose
  u16*  a_t    = (u16*)(ws + 48*MB);      // [48,56) dead after opm_fused
  u16*  b_t    = (u16*)(ws + 56*MB);      // [56,64) dead after opm_fused
  float* z_new = (float*)(ws + 64*MB);    // [64,96) fp32, dead after ln_bias
  float* bias  = (float*)(ws + 128*MB);   // [128,130)
  u16*  w_sm   = (u16*)(ws + 130*MB);     // [130,131)
  float* recip = (float*)(ws + 131*MB);   // 256 KB
  u16*  wb     = (u16*)(ws + 131*MB + 512*1024);  // 360 KB
  // stage-B per-chunk overlays (alive only after ln_bias):
  u16*  v_t  = (u16*)(ws + 16*MB);        // 32 MiB
  u16*  gbuf = (u16*)(ws + 48*MB);        // 32 MiB
  u16*  obuf = (u16*)(ws + 80*MB);        // 32 MiB

  const u16* w_ab = wb;
  const u16* owp  = wb + 4096;
  const u16* mw_b = wb + 135168;
  const u16* gw_b = wb + 151552;
  const u16* ow_b = wb + 167936;

  // ---- stage A: OPM path
  ln_m_kernel<<<dim3(NPOS/4),256,0,stream>>>(m, opm_nw, opm_nb, pwa_nmw, pwa_nmb, mn_opm, mn_pwa);
  cvt_w_kernel<<<dim3(184320/256),256,0,stream>>>(opm_aw, opm_bw, opm_ow, pwa_mw, pwa_gw, pwa_ow, wb);
  { EpiArgs ea{}; ea.rowscale = msa; ea.out_b = ab; ea.ldc = 64;
    gemm_k<128,64,2,2,4,2,EPI_ROWSCALE><<<dim3(1,NPOS/128),256,0,stream>>>(mn_opm, nullptr, w_ab, 64, 0,0, ea); }
  transpose_ab_kernel<<<dim3(8,256),256,0,stream>>>(ab, a_t, b_t);
  num_mask_kernel<<<dim3(256),256,0,stream>>>(msa, recip);
  opm_fused<<<dim3(4096),256,0,stream>>>(a_t, b_t, recip, owp, opm_ob, z, z_new);
  ln_bias_kernel<<<dim3(NPAIR/4),256,0,stream>>>(z_new, pwa_nzw, pwa_nzb, pwa_zw, pmask, bias);
  softmax_kernel<<<dim3(2048/4),256,0,stream>>>(bias, w_sm);

  // ---- stage B: PWA, s-chunked x2 (CHS=256)
  for (int sc=0; sc<2; ++sc){
    const u16* mnp = mn_pwa + (size_t)sc*CHPOS*CM;
    { EpiArgs ea{}; ea.out_b = v_t;
      gemm_k<128,128,2,2,4,4,EPI_VT><<<dim3(2,CHPOS/128),256,0,stream>>>(mnp, nullptr, mw_b, 64, 0,0, ea); }
    { EpiArgs ea{}; ea.out_b = gbuf; ea.ldc = 256;
      gemm_k<128,128,2,2,4,4,EPI_SIGMOID><<<dim3(2,CHPOS/128),256,0,stream>>>(mnp, nullptr, gw_b, 64, 0,0, ea); }
    { EpiArgs ea{}; ea.out_b = obuf;
      gemm_k<128,128,2,2,4,4,EPI_O><<<dim3((CHS*32)/128, 2, NH),256,0,stream>>>(w_sm, nullptr, v_t, 256,
            (size_t)NPAIR, (size_t)(CHS*32)*N_DIM, ea); }
    { EpiArgs ea{}; ea.out_f = out + (size_t)sc*CHPOS*CM; ea.ldc = 64;
      gemm_k<128,64,2,2,4,2,EPI_PLAIN,true><<<dim3(1,CHPOS/128),256,0,stream>>>(gbuf, obuf, ow_b, 256, 0,0, ea); }
  }
}

// Round 7
// 523.531 us; speedup vs baseline: 1.9261x; 1.0112x over previous
//
#include <hip/hip_runtime.h>
#include <stdint.h>

using u16 = unsigned short;
using u32 = unsigned int;

#define S_DIM 512
#define N_DIM 256
#define CM 64
#define CZ 128
#define NH 8
#define NPOS (S_DIM*N_DIM)       // 131072 positions (s,n)
#define NPAIR (N_DIM*N_DIM)      // 65536 pairs (i,j)
#define CHS 256                  // s-chunk (2 chunks)
#define CHPOS (CHS*N_DIM)        // 65536

__device__ __forceinline__ float b2f(u16 h){ u32 u = ((u32)h)<<16; float f; __builtin_memcpy(&f,&u,4); return f; }
__device__ __forceinline__ u16 f2b(float f){ u32 u; __builtin_memcpy(&u,&f,4); u32 r = (u + 0x7fffu + ((u>>16)&1u))>>16; return (u16)r; }

typedef __bf16 bf16_t;
typedef bf16_t bf16x8 __attribute__((ext_vector_type(8)));
typedef float  f32x4  __attribute__((ext_vector_type(4)));

typedef const __attribute__((address_space(1))) void* gvp;
typedef __attribute__((address_space(3))) void* lvp;
#define GLOAD_LDS16(g, l) __builtin_amdgcn_global_load_lds((gvp)(uintptr_t)(g), (lvp)(uintptr_t)(l), 16, 0, 0)

__device__ __forceinline__ uint4 bfmul8(uint4 a, uint4 b){
  union{uint4 v; u16 h[8];} x,y,r;
  x.v=a; y.v=b;
  #pragma unroll
  for (int k=0;k<8;k++) r.h[k] = f2b(b2f(x.h[k])*b2f(y.h[k]));
  return r.v;
}

struct EpiArgs {
  const float* rowscale;
  u16*  out_b;
  float* out_f;
  int ldc;
};

constexpr int EPI_PLAIN=0, EPI_ROWSCALE=1, EPI_SIGMOID=2, EPI_VT=3, EPI_O=6;

// C[M,N] = A[M,K] * W[N,K]^T, bf16 in, fp32 accum. BK=64.
// EPI_VT: epilogue assembles the transposed tile in LDS then writes coalesced 256B rows.
template<int BM,int BN,int WR,int WC,int FM,int FN,int EPI,bool MULA=false>
__global__ __launch_bounds__(256) void gemm_k(const u16* __restrict__ A, const u16* __restrict__ A2,
                                              const u16* __restrict__ W,
                                              int K, size_t sAz, size_t sWz, EpiArgs ea)
{
  static_assert(BM==WR*FM*16 && BN==WC*FN*16 && WR*WC==4, "geom");
  __shared__ __align__(16) u16 ls[(BM+BN)*64];
  u16* lsA = ls;
  u16* lsW = ls + BM*64;
  const int tid  = threadIdx.x;
  const int lane = tid & 63;
  const int wv   = tid >> 6;
  const int wr   = wv / WC;
  const int wc   = wv % WC;
  const int m0   = blockIdx.y * BM;
  const int n0   = blockIdx.x * BN;
  const u16* Ab  = A  + (size_t)blockIdx.z * sAz + (size_t)m0 * K;
  const u16* A2b = MULA ? (A2 + (size_t)blockIdx.z * sAz + (size_t)m0 * K) : nullptr;
  const u16* Wb  = W  + (size_t)blockIdx.z * sWz + (size_t)n0 * K;

  f32x4 acc[FM][FN];
  #pragma unroll
  for (int i=0;i<FM;i++)
    #pragma unroll
    for (int j=0;j<FN;j++) acc[i][j] = (f32x4){0.f,0.f,0.f,0.f};

  const int nkt = K >> 6;
  for (int kt = 0; kt < nkt; ++kt) {
    if constexpr (!MULA) {
      #pragma unroll
      for (int c0 = 0; c0 < BM*8; c0 += 256) {
        int cc = c0 + (wv<<6) + lane;
        int row = cc>>3, kc = cc&7;
        GLOAD_LDS16(Ab + (size_t)row*K + (kt<<6) + ((kc ^ (row&7))<<3),
                    lsA + (size_t)(c0 + (wv<<6))*8);
      }
      #pragma unroll
      for (int c0 = 0; c0 < BN*8; c0 += 256) {
        int cc = c0 + (wv<<6) + lane;
        int row = cc>>3, kc = cc&7;
        GLOAD_LDS16(Wb + (size_t)row*K + (kt<<6) + ((kc ^ (row&7))<<3),
                    lsW + (size_t)(c0 + (wv<<6))*8);
      }
    } else {
      for (int c = tid; c < (BM+BN)*8; c += 256) {
        if (c < BM*8) {
          int row = c>>3, kc = c&7;
          size_t off = (size_t)row*K + (kt<<6) + (kc<<3);
          uint4 v = *reinterpret_cast<const uint4*>(Ab + off);
          uint4 v2 = *reinterpret_cast<const uint4*>(A2b + off);
          v = bfmul8(v, v2);
          *reinterpret_cast<uint4*>((char*)lsA + row*128 + ((kc<<4) ^ ((row&7)<<4))) = v;
        } else {
          int c2 = c - BM*8; int row = c2>>3, kc = c2&7;
          uint4 v = *reinterpret_cast<const uint4*>(Wb + (size_t)row*K + (kt<<6) + (kc<<3));
          *reinterpret_cast<uint4*>((char*)lsW + row*128 + ((kc<<4) ^ ((row&7)<<4))) = v;
        }
      }
    }
    __syncthreads();
    #pragma unroll
    for (int kk=0; kk<2; ++kk) {
      const int kb = (kk<<6) + ((lane>>4)<<4);
      bf16x8 af[FM], wf[FN];
      #pragma unroll
      for (int mf=0;mf<FM;mf++){
        int row = wr*FM*16 + mf*16 + (lane&15);
        af[mf] = *reinterpret_cast<const bf16x8*>((char*)lsA + row*128 + (kb ^ ((row&7)<<4)));
      }
      #pragma unroll
      for (int nf=0;nf<FN;nf++){
        int row = wc*FN*16 + nf*16 + (lane&15);
        wf[nf] = *reinterpret_cast<const bf16x8*>((char*)lsW + row*128 + (kb ^ ((row&7)<<4)));
      }
      #pragma unroll
      for (int mf=0;mf<FM;mf++)
        #pragma unroll
        for (int nf=0;nf<FN;nf++)
          acc[mf][nf] = __builtin_amdgcn_mfma_f32_16x16x32_bf16(af[mf], wf[nf], acc[mf][nf], 0,0,0);
    }
    __syncthreads();
  }

  if constexpr (EPI==EPI_VT) {
    // assemble [128 hcrow][128 j] bf16 in ls (32 KB), XOR-swizzled, then coalesced copy.
    #pragma unroll
    for (int mf=0;mf<FM;mf++){
      #pragma unroll
      for (int nf=0;nf<FN;nf++){
        f32x4 v = acc[mf][nf];
        int hcrow = wc*FN*16 + nf*16 + (lane&15);
        int jl0   = wr*FM*16 + mf*16 + ((lane>>4)<<2);
        union { uint2 u; u16 h[4]; } pk;
        #pragma unroll
        for (int r=0;r<4;r++) pk.h[r] = f2b(v[r]);
        *reinterpret_cast<uint2*>((char*)ls + hcrow*256 + ((jl0*2) ^ ((hcrow&7)<<4))) = pk.u;
      }
    }
    __syncthreads();
    const int sl = m0>>8, j0 = m0&255, hb = n0>>5;
    #pragma unroll
    for (int itc=0; itc<8; ++itc){
      int idx = itc*256 + tid;            // 0..2047 = 128 rows x 16 chunks
      int hcrow = idx>>4, q = idx&15;
      uint4 vv = *reinterpret_cast<const uint4*>((char*)ls + hcrow*256 + ((q*16) ^ ((hcrow&7)<<4)));
      int dstrow = (hb + (hcrow>>5))*(CHS*32) + sl*32 + (hcrow&31);
      *reinterpret_cast<uint4*>(ea.out_b + (size_t)dstrow*N_DIM + j0 + q*8) = vv;
    }
  } else {
    const int hz = blockIdx.z;
    #pragma unroll
    for (int mf=0;mf<FM;mf++){
      #pragma unroll
      for (int nf=0;nf<FN;nf++){
        f32x4 v = acc[mf][nf];
        int col   = n0 + wc*FN*16 + nf*16 + (lane&15);
        int rbase = m0 + wr*FM*16 + mf*16 + ((lane>>4)<<2);
        #pragma unroll
        for (int r=0;r<4;r++){
          int row = rbase + r;
          float x = v[r];
          if constexpr (EPI==EPI_PLAIN) {
            ea.out_f[(size_t)row*ea.ldc + col] = x;
          } else if constexpr (EPI==EPI_ROWSCALE) {
            x *= ea.rowscale[row];
            ea.out_b[(size_t)row*ea.ldc + col] = f2b(x);
          } else if constexpr (EPI==EPI_SIGMOID) {
            x = 1.f/(1.f+__expf(-x));
            ea.out_b[(size_t)row*ea.ldc + col] = f2b(x);
          } else if constexpr (EPI==EPI_O) {
            int sl2 = col>>5, cc = col&31;
            ea.out_b[(size_t)(sl2*N_DIM + row)*256 + hz*32 + cc] = f2b(x);
          }
        }
      }
    }
  }
}

// ---- Fused OuterProductMean. Grid 4096; 2D XCD regions (4x2 over by x bx), by-fast inner.
// LDS 48 KB: stage1 A[0,16K B)+W[16K,32K B); epi1 zt overlays [0,32K B); stage2 slabs [32K,48K B).
// Stage 2: 16 iters x 4 KB/wave slab (64 k' each), wave-private vmcnt sync, no barriers.
__global__ __launch_bounds__(256,1) void opm_fused(const u16* __restrict__ a_t, const u16* __restrict__ b_t,
                                                   const float* __restrict__ recip, const u16* __restrict__ owp,
                                                   const float* __restrict__ obias, const float* __restrict__ z,
                                                   float* __restrict__ z_new)
{
  __shared__ __align__(16) u16 ls[24576];    // 48 KB
  const int tid = threadIdx.x, lane = tid&63, wv = tid>>6;
  const int wr = wv>>1, wc = wv&1;
  const int bid = blockIdx.x;
  const int xcd = bid&7, l = bid>>3;
  const int by = ((xcd>>1)<<4) + (l&15);     // 4 row-regions of 16 panels, by-fast
  const int bx = ((xcd&1)<<5) + (l>>4);      // 2 col-regions of 32 panels
  const u16* Ab = a_t + (size_t)by*128*S_DIM;
  const u16* Wb = b_t + (size_t)bx*128*S_DIM;
  u16* lsA = ls;
  u16* lsW = ls + 8192;

  f32x4 acc[4][4];
  #pragma unroll
  for (int i=0;i<4;i++)
    #pragma unroll
    for (int j=0;j<4;j++) acc[i][j] = (f32x4){0.f,0.f,0.f,0.f};

  // ---- stage 1: zt_tile = A(128xK) * B(128xK)^T, K=512
  for (int kt = 0; kt < 8; ++kt) {
    #pragma unroll
    for (int c0 = 0; c0 < 1024; c0 += 256) {
      int cc = c0 + (wv<<6) + lane;
      int row = cc>>3, kc = cc&7;
      size_t srcoff = (size_t)row*S_DIM + (kt<<6) + ((kc ^ (row&7))<<3);
      GLOAD_LDS16(Ab + srcoff, lsA + (size_t)(c0 + (wv<<6))*8);
      GLOAD_LDS16(Wb + srcoff, lsW + (size_t)(c0 + (wv<<6))*8);
    }
    __syncthreads();
    #pragma unroll
    for (int kk=0; kk<2; ++kk) {
      const int kb = (kk<<6) + ((lane>>4)<<4);
      bf16x8 af[4], wf[4];
      #pragma unroll
      for (int mf=0;mf<4;mf++){
        int row = wr*64 + mf*16 + (lane&15);
        af[mf] = *reinterpret_cast<const bf16x8*>((char*)lsA + row*128 + (kb ^ ((row&7)<<4)));
      }
      #pragma unroll
      for (int nf=0;nf<4;nf++){
        int row = wc*64 + nf*16 + (lane&15);
        wf[nf] = *reinterpret_cast<const bf16x8*>((char*)lsW + row*128 + (kb ^ ((row&7)<<4)));
      }
      #pragma unroll
      for (int mf=0;mf<4;mf++)
        #pragma unroll
        for (int nf=0;nf<4;nf++)
          acc[mf][nf] = __builtin_amdgcn_mfma_f32_16x16x32_bf16(af[mf], wf[nf], acc[mf][nf], 0,0,0);
    }
    __syncthreads();
  }

  // ---- epilogue 1: acc -> zt LDS (bf16, * recip), overlays ls[0,32KB)
  // zt byte(p,d,c0) = p*2048 + ((d+p)&31)*64 + ((c0*2) ^ (((d>>1)&3)<<4))
  #pragma unroll
  for (int mf=0;mf<4;mf++){
    #pragma unroll
    for (int nf=0;nf<4;nf++){
      int ii = 2*wr + (mf>>1);
      int jj = 2*wc + (nf>>1);
      int p  = ii*4 + jj;
      int d  = ((nf&1)<<4) + (lane&15);
      int c0 = ((mf&1)<<4) + ((lane>>4)<<2);
      float rv = recip[(by*4+ii)*N_DIM + bx*4 + jj];
      f32x4 v = acc[mf][nf];
      union { uint2 u; u16 h[4]; } pk;
      #pragma unroll
      for (int r=0;r<4;r++) pk.h[r] = f2b(v[r]*rv);
      int byte = p*2048 + (((d + p)&31)<<6) + ((c0*2) ^ (((d>>1)&3)<<4));
      *reinterpret_cast<uint2*>((char*)ls + byte) = pk.u;
    }
  }
  __syncthreads();

  // ---- stage 2: z_opm[16 pairs][128 z] = zt[16][1024 k'] * owp[128 z][1024 k']^T
  f32x4 acc2[2] = {(f32x4){0,0,0,0},(f32x4){0,0,0,0}};
  u16* lsw2 = ls + 16384 + wv*2048;     // 4 KB slab: [32 rows][64 u16]
  const u16* owpw = owp + wv*2048;      // rows [32wv,32wv+32) within each 8192-u16 it-block
  for (int it=0; it<16; ++it){
    #pragma unroll
    for (int j=0;j<4;j++)
      GLOAD_LDS16(owpw + (size_t)it*8192 + j*512 + lane*8, lsw2 + j*512);
    asm volatile("s_waitcnt vmcnt(0)" ::: "memory");
    __builtin_amdgcn_sched_barrier(0);
    #pragma unroll
    for (int kk=0; kk<2; ++kk){
      int d = it*2 + kk;
      int p  = lane&15;
      int c0 = (lane>>4)<<3;
      bf16x8 af = *reinterpret_cast<const bf16x8*>((char*)ls + p*2048 + (((d + p)&31)<<6) +
                    ((c0*2) ^ (((d>>1)&3)<<4)));
      const int kb = (kk<<6) + ((lane>>4)<<4);
      #pragma unroll
      for (int nf=0;nf<2;nf++){
        int rl = nf*16 + (lane&15);
        bf16x8 wf = *reinterpret_cast<const bf16x8*>((char*)lsw2 + rl*128 + (kb ^ ((rl&7)<<4)));
        acc2[nf] = __builtin_amdgcn_mfma_f32_16x16x32_bf16(af, wf, acc2[nf], 0,0,0);
      }
    }
    __builtin_amdgcn_sched_barrier(0);
  }

  // ---- epilogue 2: z_new[gp][z] = acc2 + obias + z
  #pragma unroll
  for (int nf=0;nf<2;nf++){
    int col = wv*32 + nf*16 + (lane&15);
    #pragma unroll
    for (int r=0;r<4;r++){
      int p = ((lane>>4)<<2) + r;
      size_t gp = (size_t)(by*4 + (p>>2))*N_DIM + bx*4 + (p&3);
      z_new[gp*CZ + col] = acc2[nf][r] + obias[col] + z[gp*CZ + col];
    }
  }
}

// LayerNorm of m (fp32) with BOTH param sets -> mn_opm, mn_pwa (bf16).
__global__ __launch_bounds__(256) void ln_m_kernel(const float* __restrict__ m, const float* ow, const float* ob,
                                                   const float* pw, const float* pb,
                                                   u16* __restrict__ mo, u16* __restrict__ mp)
{
  int row  = blockIdx.x*4 + (threadIdx.x>>6);
  int lane = threadIdx.x & 63;
  float x = m[(size_t)row*CM + lane];
  float s = x, s2 = x*x;
  #pragma unroll
  for (int off=32; off; off>>=1){ s += __shfl_xor(s,off); s2 += __shfl_xor(s2,off); }
  float mu   = s*(1.f/64.f);
  float var  = s2*(1.f/64.f) - mu*mu;
  float rstd = rsqrtf(var + 1e-5f);
  float mn = (x-mu)*rstd;
  mo[(size_t)row*CM+lane] = f2b(mn*ow[lane] + ob[lane]);
  mp[(size_t)row*CM+lane] = f2b(mn*pw[lane] + pb[lane]);
}

// fp32 -> bf16 weights arena.
// owp region (stage-2 DMA layout, 16 it-blocks): t = it*8192 + row*64 + kl_sw;
//   kl = kl_sw ^ ((row&7)<<3); k' = it*64 + kl; d = k'>>5, c = k'&31; v = ow[row][c*32+d].
// Layout: [0,4096) w_ab | [4096,135168) owp | [135168,151552) pwa_m_w | [151552,167936) pwa_g_w | [167936,184320) pwa_o_w
__global__ __launch_bounds__(256) void cvt_w_kernel(const float* __restrict__ aw, const float* __restrict__ bw,
                                                    const float* __restrict__ ow, const float* __restrict__ mw,
                                                    const float* __restrict__ gw, const float* __restrict__ o2w,
                                                    u16* __restrict__ wb)
{
  int e = blockIdx.x*256 + threadIdx.x;
  float v;
  if (e < 4096)        { int r = e>>6, c = e&63; v = (r<32)? aw[r*64+c] : bw[(r-32)*64+c]; }
  else if (e < 135168) { int t = e-4096; int it = t>>13, rem = t&8191, row = rem>>6, h = rem&63;
                         int kl = h ^ ((row&7)<<3);
                         int kp = it*64 + kl;
                         int d = kp>>5, c = kp&31;
                         v = ow[row*1024 + c*32 + d]; }
  else if (e < 151552) { v = mw[e-135168]; }
  else if (e < 167936) { v = gw[e-151552]; }
  else                 { v = o2w[e-167936]; }
  wb[e] = f2b(v);
}

// ab[(s,i)][c0..63] -> a_t[(i*32+c)][s] (c<32), b_t[(i*32+c-32)][s]
__global__ __launch_bounds__(256) void transpose_ab_kernel(const u16* __restrict__ ab,
                                                           u16* __restrict__ a_t, u16* __restrict__ b_t)
{
  __shared__ u16 t[64][72];
  int sb = blockIdx.x, i = blockIdx.y, tid = threadIdx.x;
  for (int c = tid; c < 512; c += 256){
    int sl = c>>3, kc = c&7;
    union { uint4 v; u16 h[8]; } u;
    u.v = *reinterpret_cast<const uint4*>(ab + ((size_t)(sb*64+sl)*N_DIM + i)*64 + (kc<<3));
    #pragma unroll
    for (int k=0;k<8;k++) t[sl][kc*8+k] = u.h[k];
  }
  __syncthreads();
  for (int c = tid; c < 512; c += 256){
    int cc = c>>3, sc = c&7;
    union { uint4 v; u16 h[8]; } u;
    #pragma unroll
    for (int k=0;k<8;k++) u.h[k] = t[sc*8+k][cc];
    u16* dst = (cc < 32) ? (a_t + (size_t)(i*32+cc)*S_DIM) : (b_t + (size_t)(i*32+cc-32)*S_DIM);
    *reinterpret_cast<uint4*>(dst + sb*64 + (sc<<3)) = u.v;
  }
}

__global__ __launch_bounds__(256) void num_mask_kernel(const float* __restrict__ msa, float* __restrict__ recip){
  int i = blockIdx.x, j = threadIdx.x;
  float s = 0.f;
  #pragma unroll 8
  for (int t=0;t<S_DIM;t++) s += msa[t*N_DIM+i] * msa[t*N_DIM+j];
  recip[i*N_DIM + j] = 1.f / fmaxf(s, 1.f);
}

// LN(z_new[128]) fp32 -> bias[h][pair] = dot(zn, z_w[h]) + (1-pm)*(-1e6)
__global__ __launch_bounds__(256) void ln_bias_kernel(const float* __restrict__ z_new, const float* zw, const float* zb,
                                                      const float* zwh, const float* pm, float* __restrict__ bias)
{
  int p    = blockIdx.x*4 + (threadIdx.x>>6);
  int lane = threadIdx.x & 63;
  const float* zr = z_new + (size_t)p*CZ;
  float x0 = zr[lane*2], x1 = zr[lane*2+1];
  float s = x0+x1, s2 = x0*x0 + x1*x1;
  #pragma unroll
  for (int off=32; off; off>>=1){ s += __shfl_xor(s,off); s2 += __shfl_xor(s2,off); }
  float mu   = s*(1.f/128.f);
  float var  = s2*(1.f/128.f) - mu*mu;
  float rstd = rsqrtf(var + 1e-5f);
  float zn0 = (x0-mu)*rstd*zw[lane*2]   + zb[lane*2];
  float zn1 = (x1-mu)*rstd*zw[lane*2+1] + zb[lane*2+1];
  float bm = (1.f - pm[p]) * (-1.0e6f);
  float outv = 0.f;
  #pragma unroll
  for (int hh=0; hh<8; hh++){
    float tp = zn0*zwh[hh*CZ + lane*2] + zn1*zwh[hh*CZ + lane*2+1];
    #pragma unroll
    for (int off=32; off; off>>=1) tp += __shfl_xor(tp,off);
    if (lane == hh) outv = tp + bm;
  }
  if (lane < 8) bias[(size_t)lane*NPAIR + p] = outv;
}

__global__ __launch_bounds__(256) void softmax_kernel(const float* __restrict__ bias, u16* __restrict__ w_sm){
  int r    = blockIdx.x*4 + (threadIdx.x>>6);   // r = h*256 + i
  int lane = threadIdx.x & 63;
  const float* src = bias + (size_t)(r>>8)*NPAIR + (size_t)(r&255)*N_DIM;
  float4 xv = *reinterpret_cast<const float4*>(src + lane*4);
  float mx = fmaxf(fmaxf(xv.x,xv.y), fmaxf(xv.z,xv.w));
  #pragma unroll
  for (int off=32; off; off>>=1) mx = fmaxf(mx, __shfl_xor(mx,off));
  float e0 = __expf(xv.x-mx), e1 = __expf(xv.y-mx), e2 = __expf(xv.z-mx), e3 = __expf(xv.w-mx);
  float s = e0+e1+e2+e3;
  #pragma unroll
  for (int off=32; off; off>>=1) s += __shfl_xor(s,off);
  float rs = 1.f/s;
  ushort4 st; st.x=f2b(e0*rs); st.y=f2b(e1*rs); st.z=f2b(e2*rs); st.w=f2b(e3*rs);
  *reinterpret_cast<ushort4*>(w_sm + (size_t)r*N_DIM + lane*4) = st;
}

extern "C" void kernel_launch(void* const* d_in, const int* in_sizes, int n_in,
                              void* d_out, int out_size, void* d_ws, size_t ws_size,
                              hipStream_t stream)
{
  const float* m      = (const float*)d_in[0];
  const float* z      = (const float*)d_in[1];
  const float* msa    = (const float*)d_in[2];
  const float* pmask  = (const float*)d_in[3];
  const float* opm_nw = (const float*)d_in[4];
  const float* opm_nb = (const float*)d_in[5];
  const float* opm_aw = (const float*)d_in[6];
  const float* opm_bw = (const float*)d_in[7];
  const float* opm_ow = (const float*)d_in[8];
  const float* opm_ob = (const float*)d_in[9];
  const float* pwa_nmw= (const float*)d_in[10];
  const float* pwa_nmb= (const float*)d_in[11];
  const float* pwa_nzw= (const float*)d_in[12];
  const float* pwa_nzb= (const float*)d_in[13];
  const float* pwa_mw = (const float*)d_in[14];
  const float* pwa_gw = (const float*)d_in[15];
  const float* pwa_zw = (const float*)d_in[16];
  const float* pwa_ow = (const float*)d_in[17];
  float* out = (float*)d_out;
  char* ws = (char*)d_ws;

  // Arenas (MiB offsets). Peak 132 MiB.
  const size_t MB = 1024*1024;
  u16*  mn_pwa = (u16*)(ws + 0);          // [0,16) whole run
  u16*  mn_opm = (u16*)(ws + 16*MB);      // [16,32) dead after ROWSCALE
  u16*  ab     = (u16*)(ws + 32*MB);      // [32,48) dead after transpose
  u16*  a_t    = (u16*)(ws + 48*MB);      // [48,56) dead after opm_fused
  u16*  b_t    = (u16*)(ws + 56*MB);      // [56,64) dead after opm_fused
  float* z_new = (float*)(ws + 64*MB);    // [64,96) fp32, dead after ln_bias
  float* bias  = (float*)(ws + 128*MB);   // [128,130)
  u16*  w_sm   = (u16*)(ws + 130*MB);     // [130,131)
  float* recip = (float*)(ws + 131*MB);   // 256 KB
  u16*  wb     = (u16*)(ws + 131*MB + 512*1024);  // 360 KB
  // stage-B per-chunk overlays (alive only after ln_bias):
  u16*  v_t  = (u16*)(ws + 16*MB);        // 32 MiB
  u16*  gbuf = (u16*)(ws + 48*MB);        // 32 MiB
  u16*  obuf = (u16*)(ws + 80*MB);        // 32 MiB

  const u16* w_ab = wb;
  const u16* owp  = wb + 4096;
  const u16* mw_b = wb + 135168;
  const u16* gw_b = wb + 151552;
  const u16* ow_b = wb + 167936;

  // ---- stage A: OPM path
  ln_m_kernel<<<dim3(NPOS/4),256,0,stream>>>(m, opm_nw, opm_nb, pwa_nmw, pwa_nmb, mn_opm, mn_pwa);
  cvt_w_kernel<<<dim3(184320/256),256,0,stream>>>(opm_aw, opm_bw, opm_ow, pwa_mw, pwa_gw, pwa_ow, wb);
  { EpiArgs ea{}; ea.rowscale = msa; ea.out_b = ab; ea.ldc = 64;
    gemm_k<128,64,2,2,4,2,EPI_ROWSCALE><<<dim3(1,NPOS/128),256,0,stream>>>(mn_opm, nullptr, w_ab, 64, 0,0, ea); }
  transpose_ab_kernel<<<dim3(8,256),256,0,stream>>>(ab, a_t, b_t);
  num_mask_kernel<<<dim3(256),256,0,stream>>>(msa, recip);
  opm_fused<<<dim3(4096),256,0,stream>>>(a_t, b_t, recip, owp, opm_ob, z, z_new);
  ln_bias_kernel<<<dim3(NPAIR/4),256,0,stream>>>(z_new, pwa_nzw, pwa_nzb, pwa_zw, pmask, bias);
  softmax_kernel<<<dim3(2048/4),256,0,stream>>>(bias, w_sm);

  // ---- stage B: PWA, s-chunked x2 (CHS=256)
  for (int sc=0; sc<2; ++sc){
    const u16* mnp = mn_pwa + (size_t)sc*CHPOS*CM;
    { EpiArgs ea{}; ea.out_b = v_t;
      gemm_k<128,128,2,2,4,4,EPI_VT><<<dim3(2,CHPOS/128),256,0,stream>>>(mnp, nullptr, mw_b, 64, 0,0, ea); }
    { EpiArgs ea{}; ea.out_b = gbuf; ea.ldc = 256;
      gemm_k<128,128,2,2,4,4,EPI_SIGMOID><<<dim3(2,CHPOS/128),256,0,stream>>>(mnp, nullptr, gw_b, 64, 0,0, ea); }
    { EpiArgs ea{}; ea.out_b = obuf;
      gemm_k<128,128,2,2,4,4,EPI_O><<<dim3((CHS*32)/128, 2, NH),256,0,stream>>>(w_sm, nullptr, v_t, 256,
            (size_t)NPAIR, (size_t)(CHS*32)*N_DIM, ea); }
    { EpiArgs ea{}; ea.out_f = out + (size_t)sc*CHPOS*CM; ea.ldc = 64;
      gemm_k<128,64,2,2,4,2,EPI_PLAIN,true><<<dim3(1,CHPOS/128),256,0,stream>>>(gbuf, obuf, ow_b, 256, 0,0, ea); }
  }
}

// Round 9
// 495.082 us; speedup vs baseline: 2.0368x; 1.0575x over previous
//
#include <hip/hip_runtime.h>
#include <stdint.h>

using u16 = unsigned short;
using u32 = unsigned int;

#define S_DIM 512
#define N_DIM 256
#define CM 64
#define CZ 128
#define NH 8
#define NPOS (S_DIM*N_DIM)       // 131072 positions (s,n)
#define NPAIR (N_DIM*N_DIM)      // 65536 pairs (i,j)
#define CHS 256                  // s-chunk (2 chunks)
#define CHPOS (CHS*N_DIM)        // 65536

__device__ __forceinline__ float b2f(u16 h){ u32 u = ((u32)h)<<16; float f; __builtin_memcpy(&f,&u,4); return f; }
__device__ __forceinline__ u16 f2b(float f){ u32 u; __builtin_memcpy(&u,&f,4); u32 r = (u + 0x7fffu + ((u>>16)&1u))>>16; return (u16)r; }

typedef __bf16 bf16_t;
typedef bf16_t bf16x8 __attribute__((ext_vector_type(8)));
typedef float  f32x4  __attribute__((ext_vector_type(4)));

typedef const __attribute__((address_space(1))) void* gvp;
typedef __attribute__((address_space(3))) void* lvp;
#define GLOAD_LDS16(g, l) __builtin_amdgcn_global_load_lds((gvp)(uintptr_t)(g), (lvp)(uintptr_t)(l), 16, 0, 0)

__device__ __forceinline__ uint4 bfmul8(uint4 a, uint4 b){
  union{uint4 v; u16 h[8];} x,y,r;
  x.v=a; y.v=b;
  #pragma unroll
  for (int k=0;k<8;k++) r.h[k] = f2b(b2f(x.h[k])*b2f(y.h[k]));
  return r.v;
}

struct EpiArgs {
  const float* rowscale;
  u16*  out_b;
  float* out_f;
  int ldc;
};

constexpr int EPI_PLAIN=0, EPI_ROWSCALE=1, EPI_SIGMOID=2, EPI_VT=3, EPI_O=6;

// C[M,N] = A[M,K] * W[N,K]^T, bf16 in, fp32 accum. BK=64. Single-buffered (short K).
template<int BM,int BN,int WR,int WC,int FM,int FN,int EPI,bool MULA>
__device__ __forceinline__ void gemm_body(const u16* __restrict__ A, const u16* __restrict__ A2,
                                          const u16* __restrict__ W,
                                          int K, size_t sAz, size_t sWz, EpiArgs ea)
{
  static_assert(BM==WR*FM*16 && BN==WC*FN*16 && WR*WC==4, "geom");
  __shared__ __align__(16) u16 ls[(BM+BN)*64];
  u16* lsA = ls;
  u16* lsW = ls + BM*64;
  const int tid  = threadIdx.x;
  const int lane = tid & 63;
  const int wv   = tid >> 6;
  const int wr   = wv / WC;
  const int wc   = wv % WC;
  const int m0   = blockIdx.y * BM;
  const int n0   = blockIdx.x * BN;
  const u16* Ab  = A  + (size_t)blockIdx.z * sAz + (size_t)m0 * K;
  const u16* A2b = MULA ? (A2 + (size_t)blockIdx.z * sAz + (size_t)m0 * K) : nullptr;
  const u16* Wb  = W  + (size_t)blockIdx.z * sWz + (size_t)n0 * K;

  f32x4 acc[FM][FN];
  #pragma unroll
  for (int i=0;i<FM;i++)
    #pragma unroll
    for (int j=0;j<FN;j++) acc[i][j] = (f32x4){0.f,0.f,0.f,0.f};

  const int nkt = K >> 6;
  for (int kt = 0; kt < nkt; ++kt) {
    if constexpr (!MULA) {
      #pragma unroll
      for (int c0 = 0; c0 < BM*8; c0 += 256) {
        int cc = c0 + (wv<<6) + lane;
        int row = cc>>3, kc = cc&7;
        GLOAD_LDS16(Ab + (size_t)row*K + (kt<<6) + ((kc ^ (row&7))<<3),
                    lsA + (size_t)(c0 + (wv<<6))*8);
      }
      #pragma unroll
      for (int c0 = 0; c0 < BN*8; c0 += 256) {
        int cc = c0 + (wv<<6) + lane;
        int row = cc>>3, kc = cc&7;
        GLOAD_LDS16(Wb + (size_t)row*K + (kt<<6) + ((kc ^ (row&7))<<3),
                    lsW + (size_t)(c0 + (wv<<6))*8);
      }
    } else {
      for (int c = tid; c < (BM+BN)*8; c += 256) {
        if (c < BM*8) {
          int row = c>>3, kc = c&7;
          size_t off = (size_t)row*K + (kt<<6) + (kc<<3);
          uint4 v = *reinterpret_cast<const uint4*>(Ab + off);
          uint4 v2 = *reinterpret_cast<const uint4*>(A2b + off);
          v = bfmul8(v, v2);
          *reinterpret_cast<uint4*>((char*)lsA + row*128 + ((kc<<4) ^ ((row&7)<<4))) = v;
        } else {
          int c2 = c - BM*8; int row = c2>>3, kc = c2&7;
          uint4 v = *reinterpret_cast<const uint4*>(Wb + (size_t)row*K + (kt<<6) + (kc<<3));
          *reinterpret_cast<uint4*>((char*)lsW + row*128 + ((kc<<4) ^ ((row&7)<<4))) = v;
        }
      }
    }
    __syncthreads();
    #pragma unroll
    for (int kk=0; kk<2; ++kk) {
      const int kb = (kk<<6) + ((lane>>4)<<4);
      bf16x8 af[FM], wf[FN];
      #pragma unroll
      for (int mf=0;mf<FM;mf++){
        int row = wr*FM*16 + mf*16 + (lane&15);
        af[mf] = *reinterpret_cast<const bf16x8*>((char*)lsA + row*128 + (kb ^ ((row&7)<<4)));
      }
      #pragma unroll
      for (int nf=0;nf<FN;nf++){
        int row = wc*FN*16 + nf*16 + (lane&15);
        wf[nf] = *reinterpret_cast<const bf16x8*>((char*)lsW + row*128 + (kb ^ ((row&7)<<4)));
      }
      #pragma unroll
      for (int mf=0;mf<FM;mf++)
        #pragma unroll
        for (int nf=0;nf<FN;nf++)
          acc[mf][nf] = __builtin_amdgcn_mfma_f32_16x16x32_bf16(af[mf], wf[nf], acc[mf][nf], 0,0,0);
    }
    __syncthreads();
  }

  if constexpr (EPI==EPI_VT) {
    // assemble [128 hcrow][128 j] bf16 in ls, XOR-swizzled, then coalesced copy.
    #pragma unroll
    for (int mf=0;mf<FM;mf++){
      #pragma unroll
      for (int nf=0;nf<FN;nf++){
        f32x4 v = acc[mf][nf];
        int hcrow = wc*FN*16 + nf*16 + (lane&15);
        int jl0   = wr*FM*16 + mf*16 + ((lane>>4)<<2);
        union { uint2 u; u16 h[4]; } pk;
        #pragma unroll
        for (int r=0;r<4;r++) pk.h[r] = f2b(v[r]);
        *reinterpret_cast<uint2*>((char*)ls + hcrow*256 + ((jl0*2) ^ ((hcrow&7)<<4))) = pk.u;
      }
    }
    __syncthreads();
    const int sl = m0>>8, j0 = m0&255, hb = n0>>5;
    #pragma unroll
    for (int itc=0; itc<8; ++itc){
      int idx = itc*256 + tid;
      int hcrow = idx>>4, q = idx&15;
      uint4 vv = *reinterpret_cast<const uint4*>((char*)ls + hcrow*256 + ((q*16) ^ ((hcrow&7)<<4)));
      int dstrow = (hb + (hcrow>>5))*(CHS*32) + sl*32 + (hcrow&31);
      *reinterpret_cast<uint4*>(ea.out_b + (size_t)dstrow*N_DIM + j0 + q*8) = vv;
    }
  } else {
    const int hz = blockIdx.z;
    #pragma unroll
    for (int mf=0;mf<FM;mf++){
      #pragma unroll
      for (int nf=0;nf<FN;nf++){
        f32x4 v = acc[mf][nf];
        int col   = n0 + wc*FN*16 + nf*16 + (lane&15);
        int rbase = m0 + wr*FM*16 + mf*16 + ((lane>>4)<<2);
        #pragma unroll
        for (int r=0;r<4;r++){
          int row = rbase + r;
          float x = v[r];
          if constexpr (EPI==EPI_PLAIN) {
            ea.out_f[(size_t)row*ea.ldc + col] = x;
          } else if constexpr (EPI==EPI_ROWSCALE) {
            x *= ea.rowscale[row];
            ea.out_b[(size_t)row*ea.ldc + col] = f2b(x);
          } else if constexpr (EPI==EPI_SIGMOID) {
            x = 1.f/(1.f+__expf(-x));
            ea.out_b[(size_t)row*ea.ldc + col] = f2b(x);
          } else if constexpr (EPI==EPI_O) {
            int sl2 = col>>5, cc = col&31;
            ea.out_b[(size_t)(sl2*N_DIM + row)*256 + hz*32 + cc] = f2b(x);
          }
        }
      }
    }
  }
}

// Named wrappers -> per-EPI rocprof visibility.
__global__ __launch_bounds__(256) void k_rowscale(const u16* A, const u16* W, EpiArgs ea){
  gemm_body<128,64,2,2,4,2,EPI_ROWSCALE,false>(A,nullptr,W,64,0,0,ea);
}
__global__ __launch_bounds__(256) void k_vt(const u16* A, const u16* W, EpiArgs ea){
  gemm_body<128,128,2,2,4,4,EPI_VT,false>(A,nullptr,W,64,0,0,ea);
}
__global__ __launch_bounds__(256) void k_sig(const u16* A, const u16* W, EpiArgs ea){
  gemm_body<128,128,2,2,4,4,EPI_SIGMOID,false>(A,nullptr,W,64,0,0,ea);
}
__global__ __launch_bounds__(256) void k_o(const u16* A, const u16* W, EpiArgs ea){
  gemm_body<128,128,2,2,4,4,EPI_O,false>(A,nullptr,W,256,(size_t)NPAIR,(size_t)(CHS*32)*N_DIM,ea);
}
__global__ __launch_bounds__(256) void k_go(const u16* A, const u16* A2, const u16* W, EpiArgs ea){
  gemm_body<128,64,2,2,4,2,EPI_PLAIN,true>(A,A2,W,256,0,0,ea);
}

// ---- Fused OuterProductMean. Grid 4096; 2D XCD regions (4x2 over by x bx), by-fast inner.
// LDS 64 KB: stage1 dbuf buf0[0,32K B) buf1[32K,64K B); epi1 zt overlays buf0;
//            stage2 double half-slabs (2 x 4 waves x 4KB) overlay buf1.
// Stage1: prefetch kt+1 into alt buf, counted vmcnt(8) (never 0 mid-loop), raw barriers.
// Stage2: wave-private double slab, counted vmcnt(4), no barriers.
__global__ __launch_bounds__(256,1) void opm_fused(const u16* __restrict__ a_t, const u16* __restrict__ b_t,
                                                   const float* __restrict__ recip, const u16* __restrict__ owp,
                                                   const float* __restrict__ obias, const float* __restrict__ z,
                                                   float* __restrict__ z_new)
{
  __shared__ __align__(16) u16 ls[32768];    // 64 KB
  const int tid = threadIdx.x, lane = tid&63, wv = tid>>6;
  const int wr = wv>>1, wc = wv&1;
  const int bid = blockIdx.x;
  const int xcd = bid&7, l = bid>>3;
  const int by = ((xcd>>1)<<4) + (l&15);     // 4 row-regions of 16 panels, by-fast
  const int bx = ((xcd&1)<<5) + (l>>4);      // 2 col-regions of 32 panels
  const u16* Ab = a_t + (size_t)by*128*S_DIM;
  const u16* Wb = b_t + (size_t)bx*128*S_DIM;
  u16* buf0 = ls;            // 16384 u16 (A:8192, W:8192)
  u16* buf1 = ls + 16384;

  f32x4 acc[4][4];
  #pragma unroll
  for (int i=0;i<4;i++)
    #pragma unroll
    for (int j=0;j<4;j++) acc[i][j] = (f32x4){0.f,0.f,0.f,0.f};

  auto stage1 = [&](u16* b, int kt){
    #pragma unroll
    for (int c0 = 0; c0 < 1024; c0 += 256) {
      int cc = c0 + (wv<<6) + lane;
      int row = cc>>3, kc = cc&7;
      size_t srcoff = (size_t)row*S_DIM + (kt<<6) + ((kc ^ (row&7))<<3);
      GLOAD_LDS16(Ab + srcoff, b + (size_t)(c0 + (wv<<6))*8);
      GLOAD_LDS16(Wb + srcoff, b + 8192 + (size_t)(c0 + (wv<<6))*8);
    }
  };

  // ---- stage 1: zt_tile = A(128xK) * B(128xK)^T, K=512; double-buffered
  stage1(buf0, 0);
  for (int kt = 0; kt < 8; ++kt) {
    u16* cur = (kt&1) ? buf1 : buf0;
    u16* nxt = (kt&1) ? buf0 : buf1;
    if (kt < 7) {
      stage1(nxt, kt+1);
      asm volatile("s_waitcnt vmcnt(8)" ::: "memory");
    } else {
      asm volatile("s_waitcnt vmcnt(0)" ::: "memory");
    }
    __builtin_amdgcn_sched_barrier(0);
    __builtin_amdgcn_s_barrier();
    __builtin_amdgcn_sched_barrier(0);
    u16* lsA = cur;
    u16* lsW = cur + 8192;
    #pragma unroll
    for (int kk=0; kk<2; ++kk) {
      const int kb = (kk<<6) + ((lane>>4)<<4);
      bf16x8 af[4], wf[4];
      #pragma unroll
      for (int mf=0;mf<4;mf++){
        int row = wr*64 + mf*16 + (lane&15);
        af[mf] = *reinterpret_cast<const bf16x8*>((char*)lsA + row*128 + (kb ^ ((row&7)<<4)));
      }
      #pragma unroll
      for (int nf=0;nf<4;nf++){
        int row = wc*64 + nf*16 + (lane&15);
        wf[nf] = *reinterpret_cast<const bf16x8*>((char*)lsW + row*128 + (kb ^ ((row&7)<<4)));
      }
      #pragma unroll
      for (int mf=0;mf<4;mf++)
        #pragma unroll
        for (int nf=0;nf<4;nf++)
          acc[mf][nf] = __builtin_amdgcn_mfma_f32_16x16x32_bf16(af[mf], wf[nf], acc[mf][nf], 0,0,0);
    }
    __builtin_amdgcn_sched_barrier(0);
    __builtin_amdgcn_s_barrier();
    __builtin_amdgcn_sched_barrier(0);
  }

  // ---- stage-2 slab 0 DMA issued early (overlaps epilogue-1 VALU). Slabs live in buf1.
  const u16* owpw = owp + wv*2048;
  auto stage2 = [&](int it){
    const u16* src = owpw + (size_t)it*8192;
    u16* dst = buf1 + ((it&1) ? 8192 : 0) + wv*2048;
    #pragma unroll
    for (int j=0;j<4;j++)
      GLOAD_LDS16(src + j*512 + lane*8, dst + j*512);
  };
  stage2(0);

  // ---- epilogue 1: acc -> zt LDS (bf16, * recip), overlays buf0
  // zt byte(p,d,c0) = p*2048 + ((d+p)&31)*64 + ((c0*2) ^ (((d>>1)&3)<<4))
  #pragma unroll
  for (int mf=0;mf<4;mf++){
    #pragma unroll
    for (int nf=0;nf<4;nf++){
      int ii = 2*wr + (mf>>1);
      int jj = 2*wc + (nf>>1);
      int p  = ii*4 + jj;
      int d  = ((nf&1)<<4) + (lane&15);
      int c0 = ((mf&1)<<4) + ((lane>>4)<<2);
      float rv = recip[(by*4+ii)*N_DIM + bx*4 + jj];
      f32x4 v = acc[mf][nf];
      union { uint2 u; u16 h[4]; } pk;
      #pragma unroll
      for (int r=0;r<4;r++) pk.h[r] = f2b(v[r]*rv);
      int byte = p*2048 + (((d + p)&31)<<6) + ((c0*2) ^ (((d>>1)&3)<<4));
      *reinterpret_cast<uint2*>((char*)ls + byte) = pk.u;
    }
  }
  asm volatile("s_waitcnt lgkmcnt(0)" ::: "memory");
  __builtin_amdgcn_s_barrier();
  __builtin_amdgcn_sched_barrier(0);

  // ---- stage 2: z_opm[16 pairs][128 z] = zt[16][1024 k'] * owp[128 z][1024 k']^T
  f32x4 acc2[2] = {(f32x4){0,0,0,0},(f32x4){0,0,0,0}};
  for (int it=0; it<16; ++it){
    if (it < 15){
      stage2(it+1);
      asm volatile("s_waitcnt vmcnt(4)" ::: "memory");
    } else {
      asm volatile("s_waitcnt vmcnt(0)" ::: "memory");
    }
    __builtin_amdgcn_sched_barrier(0);
    u16* sl2 = buf1 + ((it&1) ? 8192 : 0) + wv*2048;
    #pragma unroll
    for (int kk=0; kk<2; ++kk){
      int d = it*2 + kk;
      int p  = lane&15;
      int c0 = (lane>>4)<<3;
      bf16x8 af = *reinterpret_cast<const bf16x8*>((char*)ls + p*2048 + (((d + p)&31)<<6) +
                    ((c0*2) ^ (((d>>1)&3)<<4)));
      const int kb = (kk<<6) + ((lane>>4)<<4);
      #pragma unroll
      for (int nf=0;nf<2;nf++){
        int rl = nf*16 + (lane&15);
        bf16x8 wf = *reinterpret_cast<const bf16x8*>((char*)sl2 + rl*128 + (kb ^ ((rl&7)<<4)));
        acc2[nf] = __builtin_amdgcn_mfma_f32_16x16x32_bf16(af, wf, acc2[nf], 0,0,0);
      }
    }
    __builtin_amdgcn_sched_barrier(0);
  }

  // ---- epilogue 2: z_new[gp][z] = acc2 + obias + z
  #pragma unroll
  for (int nf=0;nf<2;nf++){
    int col = wv*32 + nf*16 + (lane&15);
    #pragma unroll
    for (int r=0;r<4;r++){
      int p = ((lane>>4)<<2) + r;
      size_t gp = (size_t)(by*4 + (p>>2))*N_DIM + bx*4 + (p&3);
      z_new[gp*CZ + col] = acc2[nf][r] + obias[col] + z[gp*CZ + col];
    }
  }
}

// LayerNorm of m (fp32) with BOTH param sets -> mn_opm, mn_pwa (bf16).
__global__ __launch_bounds__(256) void ln_m_kernel(const float* __restrict__ m, const float* ow, const float* ob,
                                                   const float* pw, const float* pb,
                                                   u16* __restrict__ mo, u16* __restrict__ mp)
{
  int row  = blockIdx.x*4 + (threadIdx.x>>6);
  int lane = threadIdx.x & 63;
  float x = m[(size_t)row*CM + lane];
  float s = x, s2 = x*x;
  #pragma unroll
  for (int off=32; off; off>>=1){ s += __shfl_xor(s,off); s2 += __shfl_xor(s2,off); }
  float mu   = s*(1.f/64.f);
  float var  = s2*(1.f/64.f) - mu*mu;
  float rstd = rsqrtf(var + 1e-5f);
  float mn = (x-mu)*rstd;
  mo[(size_t)row*CM+lane] = f2b(mn*ow[lane] + ob[lane]);
  mp[(size_t)row*CM+lane] = f2b(mn*pw[lane] + pb[lane]);
}

// fp32 -> bf16 weights arena.
// owp region (stage-2 DMA layout, 16 it-blocks): t = it*8192 + row*64 + kl_sw;
//   kl = kl_sw ^ ((row&7)<<3); k' = it*64 + kl; d = k'>>5, c = k'&31; v = ow[row][c*32+d].
// Layout: [0,4096) w_ab | [4096,135168) owp | [135168,151552) pwa_m_w | [151552,167936) pwa_g_w | [167936,184320) pwa_o_w
__global__ __launch_bounds__(256) void cvt_w_kernel(const float* __restrict__ aw, const float* __restrict__ bw,
                                                    const float* __restrict__ ow, const float* __restrict__ mw,
                                                    const float* __restrict__ gw, const float* __restrict__ o2w,
                                                    u16* __restrict__ wb)
{
  int e = blockIdx.x*256 + threadIdx.x;
  float v;
  if (e < 4096)        { int r = e>>6, c = e&63; v = (r<32)? aw[r*64+c] : bw[(r-32)*64+c]; }
  else if (e < 135168) { int t = e-4096; int it = t>>13, rem = t&8191, row = rem>>6, h = rem&63;
                         int kl = h ^ ((row&7)<<3);
                         int kp = it*64 + kl;
                         int d = kp>>5, c = kp&31;
                         v = ow[row*1024 + c*32 + d]; }
  else if (e < 151552) { v = mw[e-135168]; }
  else if (e < 167936) { v = gw[e-151552]; }
  else                 { v = o2w[e-167936]; }
  wb[e] = f2b(v);
}

// ab[(s,i)][c0..63] -> a_t[(i*32+c)][s] (c<32), b_t[(i*32+c-32)][s]
__global__ __launch_bounds__(256) void transpose_ab_kernel(const u16* __restrict__ ab,
                                                           u16* __restrict__ a_t, u16* __restrict__ b_t)
{
  __shared__ u16 t[64][72];
  int sb = blockIdx.x, i = blockIdx.y, tid = threadIdx.x;
  for (int c = tid; c < 512; c += 256){
    int sl = c>>3, kc = c&7;
    union { uint4 v; u16 h[8]; } u;
    u.v = *reinterpret_cast<const uint4*>(ab + ((size_t)(sb*64+sl)*N_DIM + i)*64 + (kc<<3));
    #pragma unroll
    for (int k=0;k<8;k++) t[sl][kc*8+k] = u.h[k];
  }
  __syncthreads();
  for (int c = tid; c < 512; c += 256){
    int cc = c>>3, sc = c&7;
    union { uint4 v; u16 h[8]; } u;
    #pragma unroll
    for (int k=0;k<8;k++) u.h[k] = t[sc*8+k][cc];
    u16* dst = (cc < 32) ? (a_t + (size_t)(i*32+cc)*S_DIM) : (b_t + (size_t)(i*32+cc-32)*S_DIM);
    *reinterpret_cast<uint4*>(dst + sb*64 + (sc<<3)) = u.v;
  }
}

__global__ __launch_bounds__(256) void num_mask_kernel(const float* __restrict__ msa, float* __restrict__ recip){
  int i = blockIdx.x, j = threadIdx.x;
  float s = 0.f;
  #pragma unroll 8
  for (int t=0;t<S_DIM;t++) s += msa[t*N_DIM+i] * msa[t*N_DIM+j];
  recip[i*N_DIM + j] = 1.f / fmaxf(s, 1.f);
}

// LN(z_new[128]) fp32 -> bias[h][pair] = dot(zn, z_w[h]) + (1-pm)*(-1e6)
__global__ __launch_bounds__(256) void ln_bias_kernel(const float* __restrict__ z_new, const float* zw, const float* zb,
                                                      const float* zwh, const float* pm, float* __restrict__ bias)
{
  int p    = blockIdx.x*4 + (threadIdx.x>>6);
  int lane = threadIdx.x & 63;
  const float* zr = z_new + (size_t)p*CZ;
  float x0 = zr[lane*2], x1 = zr[lane*2+1];
  float s = x0+x1, s2 = x0*x0 + x1*x1;
  #pragma unroll
  for (int off=32; off; off>>=1){ s += __shfl_xor(s,off); s2 += __shfl_xor(s2,off); }
  float mu   = s*(1.f/128.f);
  float var  = s2*(1.f/128.f) - mu*mu;
  float rstd = rsqrtf(var + 1e-5f);
  float zn0 = (x0-mu)*rstd*zw[lane*2]   + zb[lane*2];
  float zn1 = (x1-mu)*rstd*zw[lane*2+1] + zb[lane*2+1];
  float bm = (1.f - pm[p]) * (-1.0e6f);
  float outv = 0.f;
  #pragma unroll
  for (int hh=0; hh<8; hh++){
    float tp = zn0*zwh[hh*CZ + lane*2] + zn1*zwh[hh*CZ + lane*2+1];
    #pragma unroll
    for (int off=32; off; off>>=1) tp += __shfl_xor(tp,off);
    if (lane == hh) outv = tp + bm;
  }
  if (lane < 8) bias[(size_t)lane*NPAIR + p] = outv;
}

__global__ __launch_bounds__(256) void softmax_kernel(const float* __restrict__ bias, u16* __restrict__ w_sm){
  int r    = blockIdx.x*4 + (threadIdx.x>>6);   // r = h*256 + i
  int lane = threadIdx.x & 63;
  const float* src = bias + (size_t)(r>>8)*NPAIR + (size_t)(r&255)*N_DIM;
  float4 xv = *reinterpret_cast<const float4*>(src + lane*4);
  float mx = fmaxf(fmaxf(xv.x,xv.y), fmaxf(xv.z,xv.w));
  #pragma unroll
  for (int off=32; off; off>>=1) mx = fmaxf(mx, __shfl_xor(mx,off));
  float e0 = __expf(xv.x-mx), e1 = __expf(xv.y-mx), e2 = __expf(xv.z-mx), e3 = __expf(xv.w-mx);
  float s = e0+e1+e2+e3;
  #pragma unroll
  for (int off=32; off; off>>=1) s += __shfl_xor(s,off);
  float rs = 1.f/s;
  ushort4 st; st.x=f2b(e0*rs); st.y=f2b(e1*rs); st.z=f2b(e2*rs); st.w=f2b(e3*rs);
  *reinterpret_cast<ushort4*>(w_sm + (size_t)r*N_DIM + lane*4) = st;
}

extern "C" void kernel_launch(void* const* d_in, const int* in_sizes, int n_in,
                              void* d_out, int out_size, void* d_ws, size_t ws_size,
                              hipStream_t stream)
{
  const float* m      = (const float*)d_in[0];
  const float* z      = (const float*)d_in[1];
  const float* msa    = (const float*)d_in[2];
  const float* pmask  = (const float*)d_in[3];
  const float* opm_nw = (const float*)d_in[4];
  const float* opm_nb = (const float*)d_in[5];
  const float* opm_aw = (const float*)d_in[6];
  const float* opm_bw = (const float*)d_in[7];
  const float* opm_ow = (const float*)d_in[8];
  const float* opm_ob = (const float*)d_in[9];
  const float* pwa_nmw= (const float*)d_in[10];
  const float* pwa_nmb= (const float*)d_in[11];
  const float* pwa_nzw= (const float*)d_in[12];
  const float* pwa_nzb= (const float*)d_in[13];
  const float* pwa_mw = (const float*)d_in[14];
  const float* pwa_gw = (const float*)d_in[15];
  const float* pwa_zw = (const float*)d_in[16];
  const float* pwa_ow = (const float*)d_in[17];
  float* out = (float*)d_out;
  char* ws = (char*)d_ws;

  // Arenas (MiB offsets). Peak 132 MiB.
  const size_t MB = 1024*1024;
  u16*  mn_pwa = (u16*)(ws + 0);          // [0,16) whole run
  u16*  mn_opm = (u16*)(ws + 16*MB);      // [16,32) dead after ROWSCALE
  u16*  ab     = (u16*)(ws + 32*MB);      // [32,48) dead after transpose
  u16*  a_t    = (u16*)(ws + 48*MB);      // [48,56) dead after opm_fused
  u16*  b_t    = (u16*)(ws + 56*MB);      // [56,64) dead after opm_fused
  float* z_new = (float*)(ws + 64*MB);    // [64,96) fp32, dead after ln_bias
  float* bias  = (float*)(ws + 128*MB);   // [128,130)
  u16*  w_sm   = (u16*)(ws + 130*MB);     // [130,131)
  float* recip = (float*)(ws + 131*MB);   // 256 KB
  u16*  wb     = (u16*)(ws + 131*MB + 512*1024);  // 360 KB
  // stage-B per-chunk overlays (alive only after ln_bias):
  u16*  v_t  = (u16*)(ws + 16*MB);        // 32 MiB
  u16*  gbuf = (u16*)(ws + 48*MB);        // 32 MiB
  u16*  obuf = (u16*)(ws + 80*MB);        // 32 MiB

  const u16* w_ab = wb;
  const u16* owp  = wb + 4096;
  const u16* mw_b = wb + 135168;
  const u16* gw_b = wb + 151552;
  const u16* ow_b = wb + 167936;

  // ---- stage A: OPM path
  ln_m_kernel<<<dim3(NPOS/4),256,0,stream>>>(m, opm_nw, opm_nb, pwa_nmw, pwa_nmb, mn_opm, mn_pwa);
  cvt_w_kernel<<<dim3(184320/256),256,0,stream>>>(opm_aw, opm_bw, opm_ow, pwa_mw, pwa_gw, pwa_ow, wb);
  { EpiArgs ea{}; ea.rowscale = msa; ea.out_b = ab; ea.ldc = 64;
    k_rowscale<<<dim3(1,NPOS/128),256,0,stream>>>(mn_opm, w_ab, ea); }
  transpose_ab_kernel<<<dim3(8,256),256,0,stream>>>(ab, a_t, b_t);
  num_mask_kernel<<<dim3(256),256,0,stream>>>(msa, recip);
  opm_fused<<<dim3(4096),256,0,stream>>>(a_t, b_t, recip, owp, opm_ob, z, z_new);
  ln_bias_kernel<<<dim3(NPAIR/4),256,0,stream>>>(z_new, pwa_nzw, pwa_nzb, pwa_zw, pmask, bias);
  softmax_kernel<<<dim3(2048/4),256,0,stream>>>(bias, w_sm);

  // ---- stage B: PWA, s-chunked x2 (CHS=256)
  for (int sc=0; sc<2; ++sc){
    const u16* mnp = mn_pwa + (size_t)sc*CHPOS*CM;
    { EpiArgs ea{}; ea.out_b = v_t;
      k_vt<<<dim3(2,CHPOS/128),256,0,stream>>>(mnp, mw_b, ea); }
    { EpiArgs ea{}; ea.out_b = gbuf; ea.ldc = 256;
      k_sig<<<dim3(2,CHPOS/128),256,0,stream>>>(mnp, gw_b, ea); }
    { EpiArgs ea{}; ea.out_b = obuf;
      k_o<<<dim3((CHS*32)/128, 2, NH),256,0,stream>>>(w_sm, v_t, ea); }
    { EpiArgs ea{}; ea.out_f = out + (size_t)sc*CHPOS*CM; ea.ldc = 64;
      k_go<<<dim3(1,CHPOS/128),256,0,stream>>>(gbuf, obuf, ow_b, ea); }
  }
}